// Round 1
// baseline (953.258 us; speedup 1.0000x reference)
//
#include <hip/hip_runtime.h>
#include <hip/hip_bf16.h>

// RGCN regression: N=50000 nodes, E=800000 edges, R=8 relations, C=H=128.
// Strategy (round 0, fp32-correct baseline):
//  1) counting-sort edges by dst (hist + 1-block scan + scatter, int atomics only)
//  2) per layer: wave-per-node aggregation -> agg[N, R*C] normalized means (no fp atomics)
//  3) per layer: tiled fp32 GEMM  out[N,128] = bias + x@root + agg@Wflat  (K=1152), fused relu
//  4) final dot with Wout + bout

constexpr int NN = 50000;
constexpr int EE = 800000;
constexpr int RR = 8;
constexpr int CC = 128;   // == H

// ---------------- histogram ----------------
__global__ void hist_kernel(const int* __restrict__ dst, int* __restrict__ cnt) {
    int e = blockIdx.x * blockDim.x + threadIdx.x;
    if (e < EE) atomicAdd(&cnt[dst[e]], 1);
}

// ---------------- single-block exclusive scan over N counts ----------------
__global__ __launch_bounds__(1024) void scan_kernel(const int* __restrict__ cnt,
                                                    int* __restrict__ off,
                                                    int* __restrict__ cursor) {
    __shared__ int partial[1024];
    const int t = threadIdx.x;
    const int chunk = (NN + 1023) >> 10;          // 49
    const int lo = t * chunk;
    const int hi = min(lo + chunk, NN);
    int sum = 0;
    for (int i = lo; i < hi; ++i) sum += cnt[i];
    partial[t] = sum;
    __syncthreads();
    // Hillis-Steele inclusive scan
    for (int d = 1; d < 1024; d <<= 1) {
        int v = (t >= d) ? partial[t - d] : 0;
        __syncthreads();
        partial[t] += v;
        __syncthreads();
    }
    int run = (t == 0) ? 0 : partial[t - 1];
    for (int i = lo; i < hi; ++i) {
        off[i] = run; cursor[i] = run;
        run += cnt[i];
    }
    if (hi == NN) off[NN] = run;   // == EE (several threads write same value)
}

// ---------------- scatter: packed = (etype<<16)|src, sorted by dst ----------------
__global__ void scatter_kernel(const int* __restrict__ src, const int* __restrict__ dst,
                               const int* __restrict__ et, int* __restrict__ cursor,
                               int* __restrict__ packed) {
    int e = blockIdx.x * blockDim.x + threadIdx.x;
    if (e < EE) {
        int d = dst[e];
        int pos = atomicAdd(&cursor[d], 1);
        packed[pos] = (et[e] << 16) | src[e];
    }
}

// ---------------- aggregation: one wave per node ----------------
// agg[n, r*128 + c] = (sum over edges (src->n, rel r) of feat[src][c]) / max(cnt,1)
__global__ __launch_bounds__(256) void agg_kernel(const int* __restrict__ off,
                                                  const int* __restrict__ packed,
                                                  const float* __restrict__ feat,
                                                  float* __restrict__ agg) {
    const int wid = (blockIdx.x * blockDim.x + threadIdx.x) >> 6;
    if (wid >= NN) return;
    const int lane = threadIdx.x & 63;
    const int s = off[wid], e = off[wid + 1];

    float2 a0{0,0},a1{0,0},a2{0,0},a3{0,0},a4{0,0},a5{0,0},a6{0,0},a7{0,0};
    int c0=0,c1=0,c2=0,c3=0,c4=0,c5=0,c6=0,c7=0;

    int p = (s < e) ? packed[s] : 0;
    for (int i = s; i < e; ++i) {
        int pn = (i + 1 < e) ? packed[i + 1] : 0;      // prefetch next
        const float2 v = *reinterpret_cast<const float2*>(
            feat + (size_t)(p & 0xFFFF) * 128 + (lane << 1));
        switch (p >> 16) {                              // wave-uniform branch, static indices
            case 0: a0.x+=v.x; a0.y+=v.y; ++c0; break;
            case 1: a1.x+=v.x; a1.y+=v.y; ++c1; break;
            case 2: a2.x+=v.x; a2.y+=v.y; ++c2; break;
            case 3: a3.x+=v.x; a3.y+=v.y; ++c3; break;
            case 4: a4.x+=v.x; a4.y+=v.y; ++c4; break;
            case 5: a5.x+=v.x; a5.y+=v.y; ++c5; break;
            case 6: a6.x+=v.x; a6.y+=v.y; ++c6; break;
            default: a7.x+=v.x; a7.y+=v.y; ++c7; break;
        }
        p = pn;
    }
    float* o = agg + (size_t)wid * 1024 + (lane << 1);
#define WR(r) { float inv = 1.0f / (float)((c##r > 0) ? c##r : 1); \
                float2 w; w.x = a##r.x * inv; w.y = a##r.y * inv;  \
                *reinterpret_cast<float2*>(o + (r) * 128) = w; }
    WR(0) WR(1) WR(2) WR(3) WR(4) WR(5) WR(6) WR(7)
#undef WR
}

// ---------------- fused GEMM: out = relu(bias + Ax@Broot + Aagg@Bw) ----------------
// Ax [N,128], Aagg [N,1024], Broot [128,128], Bw [1024,128]
__global__ __launch_bounds__(256) void gemm_kernel(const float* __restrict__ Ax,
                                                   const float* __restrict__ Aagg,
                                                   const float* __restrict__ Broot,
                                                   const float* __restrict__ Bw,
                                                   const float* __restrict__ bias,
                                                   float* __restrict__ outp) {
    __shared__ float As[64][36];    // 64 rows x 32 k, padded to 36 for bank spread
    __shared__ float Bs[32][128];
    const int t  = threadIdx.x;
    const int n0 = blockIdx.x * 64;
    const int rg = t >> 4;               // 0..15 -> rows rg*4..rg*4+3
    const int cg = (t & 15) << 3;        // 0..120, 8 cols
    const int ar = t >> 2, ac = (t & 3) << 3;   // A staging: row ar, 8 floats at ac
    const int br = t >> 3, bc = (t & 7) << 4;   // B staging: row br, 16 floats at bc
    const int an = n0 + ar;

    float acc[4][8];
#pragma unroll
    for (int i = 0; i < 4; ++i)
#pragma unroll
        for (int j = 0; j < 8; ++j) acc[i][j] = 0.f;

    auto tile = [&](const float* __restrict__ A, int lda, int kA, const float* __restrict__ B) {
        float4 v0{0,0,0,0}, v1{0,0,0,0};
        if (an < NN) {
            const float* p = A + (size_t)an * lda + kA + ac;
            v0 = *reinterpret_cast<const float4*>(p);
            v1 = *reinterpret_cast<const float4*>(p + 4);
        }
        const float* q = B + br * 128 + bc;
        const float4 w0 = reinterpret_cast<const float4*>(q)[0];
        const float4 w1 = reinterpret_cast<const float4*>(q)[1];
        const float4 w2 = reinterpret_cast<const float4*>(q)[2];
        const float4 w3 = reinterpret_cast<const float4*>(q)[3];
        __syncthreads();   // previous tile's reads done before overwrite
        *reinterpret_cast<float4*>(&As[ar][ac])     = v0;
        *reinterpret_cast<float4*>(&As[ar][ac + 4]) = v1;
        *reinterpret_cast<float4*>(&Bs[br][bc])      = w0;
        *reinterpret_cast<float4*>(&Bs[br][bc + 4])  = w1;
        *reinterpret_cast<float4*>(&Bs[br][bc + 8])  = w2;
        *reinterpret_cast<float4*>(&Bs[br][bc + 12]) = w3;
        __syncthreads();
#pragma unroll
        for (int kk = 0; kk < 32; ++kk) {
            const float av[4] = { As[(rg<<2)+0][kk], As[(rg<<2)+1][kk],
                                  As[(rg<<2)+2][kk], As[(rg<<2)+3][kk] };
            const float4 b0 = *reinterpret_cast<const float4*>(&Bs[kk][cg]);
            const float4 b1 = *reinterpret_cast<const float4*>(&Bs[kk][cg + 4]);
            const float bv[8] = { b0.x, b0.y, b0.z, b0.w, b1.x, b1.y, b1.z, b1.w };
#pragma unroll
            for (int i = 0; i < 4; ++i)
#pragma unroll
                for (int j = 0; j < 8; ++j)
                    acc[i][j] = fmaf(av[i], bv[j], acc[i][j]);
        }
    };

#pragma unroll 1
    for (int kt = 0; kt < 4; ++kt)  tile(Ax,   128,  kt * 32, Broot + kt * 32 * 128);
#pragma unroll 1
    for (int kt = 0; kt < 32; ++kt) tile(Aagg, 1024, kt * 32, Bw    + kt * 32 * 128);

    const float4 bb0 = *reinterpret_cast<const float4*>(bias + cg);
    const float4 bb1 = *reinterpret_cast<const float4*>(bias + cg + 4);
    const float bbv[8] = { bb0.x, bb0.y, bb0.z, bb0.w, bb1.x, bb1.y, bb1.z, bb1.w };
#pragma unroll
    for (int i = 0; i < 4; ++i) {
        const int n = n0 + (rg << 2) + i;
        if (n < NN) {
            float r[8];
#pragma unroll
            for (int j = 0; j < 8; ++j) r[j] = fmaxf(acc[i][j] + bbv[j], 0.f);
            float* po = outp + (size_t)n * 128 + cg;
            *reinterpret_cast<float4*>(po)     = make_float4(r[0], r[1], r[2], r[3]);
            *reinterpret_cast<float4*>(po + 4) = make_float4(r[4], r[5], r[6], r[7]);
        }
    }
}

// ---------------- final: out[n] = h2[n] . Wout + bout ----------------
__global__ __launch_bounds__(256) void out_kernel(const float* __restrict__ h2,
                                                  const float* __restrict__ Wout,
                                                  const float* __restrict__ bout,
                                                  float* __restrict__ outp) {
    const int wid = (blockIdx.x * blockDim.x + threadIdx.x) >> 6;
    if (wid >= NN) return;
    const int lane = threadIdx.x & 63;
    const float2 v = *reinterpret_cast<const float2*>(h2 + (size_t)wid * 128 + (lane << 1));
    const float2 w = *reinterpret_cast<const float2*>(Wout + (lane << 1));
    float s = fmaf(v.x, w.x, v.y * w.y);
#pragma unroll
    for (int d = 32; d > 0; d >>= 1) s += __shfl_down(s, d, 64);
    if (lane == 0) outp[wid] = s + bout[0];
}

extern "C" void kernel_launch(void* const* d_in, const int* in_sizes, int n_in,
                              void* d_out, int out_size, void* d_ws, size_t ws_size,
                              hipStream_t stream) {
    const float* x     = (const float*)d_in[0];
    const int*   eidx  = (const int*)  d_in[1];
    const int*   etype = (const int*)  d_in[2];
    const float* W1    = (const float*)d_in[3];
    const float* root1 = (const float*)d_in[4];
    const float* b1    = (const float*)d_in[5];
    const float* W2    = (const float*)d_in[6];
    const float* root2 = (const float*)d_in[7];
    const float* b2    = (const float*)d_in[8];
    const float* Wout  = (const float*)d_in[9];
    const float* bout  = (const float*)d_in[10];
    float* out = (float*)d_out;

    const int* src = eidx;        // edge_index[0,:]
    const int* dst = eidx + EE;   // edge_index[1,:]

    // workspace layout (256B aligned), total ~260 MB
    char* ws = (char*)d_ws;
    size_t pos = 0;
    auto take = [&](size_t bytes) {
        char* p = ws + pos;
        pos = (pos + bytes + 255) & ~(size_t)255;
        return p;
    };
    int*   cnt    = (int*)  take((size_t)NN * 4);
    int*   off    = (int*)  take((size_t)(NN + 1) * 4);
    int*   cursor = (int*)  take((size_t)NN * 4);
    int*   packed = (int*)  take((size_t)EE * 4);
    float* agg    = (float*)take((size_t)NN * 1024 * 4);
    float* h1     = (float*)take((size_t)NN * 128 * 4);
    float* h2     = (float*)take((size_t)NN * 128 * 4);
    (void)ws_size; (void)n_in; (void)in_sizes; (void)out_size;

    const int eblocks = (EE + 255) / 256;          // 3125
    const int wblocks = (NN + 3) / 4;              // 12500 (wave-per-node, 4 waves/block)
    const int gblocks = (NN + 63) / 64;            // 782

    hipMemsetAsync(cnt, 0, (size_t)NN * 4, stream);
    hist_kernel   <<<eblocks, 256, 0, stream>>>(dst, cnt);
    scan_kernel   <<<1, 1024, 0, stream>>>(cnt, off, cursor);
    scatter_kernel<<<eblocks, 256, 0, stream>>>(src, dst, etype, cursor, packed);

    // layer 1
    agg_kernel <<<wblocks, 256, 0, stream>>>(off, packed, x, agg);
    gemm_kernel<<<gblocks, 256, 0, stream>>>(x, agg, root1, W1, b1, h1);
    // layer 2
    agg_kernel <<<wblocks, 256, 0, stream>>>(off, packed, h1, agg);
    gemm_kernel<<<gblocks, 256, 0, stream>>>(h1, agg, root2, W2, b2, h2);
    // output head
    out_kernel <<<wblocks, 256, 0, stream>>>(h2, Wout, bout, out);
}

// Round 2
// 640.092 us; speedup vs baseline: 1.4893x; 1.4893x over previous
//
#include <hip/hip_runtime.h>
#include <hip/hip_bf16.h>

// RGCN regression: N=50000, E=800000, R=8, C=H=128.
// Round 2: bf16 MFMA GEMM (32x32x16), bf16 feature/agg pipeline.
//  1) counting-sort edges by dst (int atomics only)
//  2) cvt x -> bf16; transpose+cvt weights -> Bt[n][k] bf16 (k = [root | W0..W7])
//  3) per layer: wave-per-node aggregation (bf16 gather, fp32 accum, bf16 agg out)
//  4) per layer: MFMA GEMM  h = relu(bias + [xb|agg] @ Bt^T), bf16 out, fp32 accum
//  5) head: wave-per-node dot with Wout (fp32)

constexpr int NN = 50000;
constexpr int EE = 800000;

typedef __attribute__((ext_vector_type(8))) short bf16x8;
typedef __attribute__((ext_vector_type(16))) float f32x16;

static __device__ __forceinline__ ushort f2bf(float f) {
    uint u = __float_as_uint(f);
    uint r = (u + 0x7fffu + ((u >> 16) & 1u)) >> 16;   // RTNE
    return (ushort)r;
}
static __device__ __forceinline__ float bflo(uint v) { return __uint_as_float(v << 16); }
static __device__ __forceinline__ float bfhi(uint v) { return __uint_as_float(v & 0xffff0000u); }

// ---------------- histogram ----------------
__global__ void hist_kernel(const int* __restrict__ dst, int* __restrict__ cnt) {
    int e = blockIdx.x * blockDim.x + threadIdx.x;
    if (e < EE) atomicAdd(&cnt[dst[e]], 1);
}

// ---------------- single-block exclusive scan ----------------
__global__ __launch_bounds__(1024) void scan_kernel(const int* __restrict__ cnt,
                                                    int* __restrict__ off,
                                                    int* __restrict__ cursor) {
    __shared__ int partial[1024];
    const int t = threadIdx.x;
    const int chunk = (NN + 1023) >> 10;
    const int lo = t * chunk;
    const int hi = min(lo + chunk, NN);
    int sum = 0;
    for (int i = lo; i < hi; ++i) sum += cnt[i];
    partial[t] = sum;
    __syncthreads();
    for (int d = 1; d < 1024; d <<= 1) {
        int v = (t >= d) ? partial[t - d] : 0;
        __syncthreads();
        partial[t] += v;
        __syncthreads();
    }
    int run = (t == 0) ? 0 : partial[t - 1];
    for (int i = lo; i < hi; ++i) {
        off[i] = run; cursor[i] = run;
        run += cnt[i];
    }
    if (hi == NN) off[NN] = run;
}

// ---------------- scatter: packed = (etype<<16)|src, grouped by dst ----------------
__global__ void scatter_kernel(const int* __restrict__ src, const int* __restrict__ dst,
                               const int* __restrict__ et, int* __restrict__ cursor,
                               int* __restrict__ packed) {
    int e = blockIdx.x * blockDim.x + threadIdx.x;
    if (e < EE) {
        int d = dst[e];
        int pos = atomicAdd(&cursor[d], 1);
        packed[pos] = (et[e] << 16) | src[e];
    }
}

// ---------------- x fp32 -> bf16 ----------------
__global__ __launch_bounds__(256) void cvt_x_kernel(const float* __restrict__ x,
                                                    ushort* __restrict__ xb) {
    const int tid = blockIdx.x * blockDim.x + threadIdx.x;   // 800000 threads, 8 elems each
    const size_t i = (size_t)tid * 8;
    const float4 v0 = *reinterpret_cast<const float4*>(x + i);
    const float4 v1 = *reinterpret_cast<const float4*>(x + i + 4);
    uint4 o;
    o.x = (uint)f2bf(v0.x) | ((uint)f2bf(v0.y) << 16);
    o.y = (uint)f2bf(v0.z) | ((uint)f2bf(v0.w) << 16);
    o.z = (uint)f2bf(v1.x) | ((uint)f2bf(v1.y) << 16);
    o.w = (uint)f2bf(v1.z) | ((uint)f2bf(v1.w) << 16);
    *reinterpret_cast<uint4*>(xb + i) = o;
}

// ---------------- weights -> Bt[n][k] bf16, k = [root(128) | W(1024)] ----------------
__global__ __launch_bounds__(256) void prep_w_kernel(const float* __restrict__ root1,
                                                     const float* __restrict__ W1,
                                                     const float* __restrict__ root2,
                                                     const float* __restrict__ W2,
                                                     ushort* __restrict__ Bt1,
                                                     ushort* __restrict__ Bt2) {
    const float* root = blockIdx.y ? root2 : root1;
    const float* W    = blockIdx.y ? W2 : W1;
    ushort* Bt        = blockIdx.y ? Bt2 : Bt1;
    const int n = blockIdx.x;                       // 0..127 output col
    for (int k = threadIdx.x; k < 1152; k += 256) {
        float v = (k < 128) ? root[(size_t)k * 128 + n]
                            : W[(size_t)(k - 128) * 128 + n];
        Bt[(size_t)n * 1152 + k] = f2bf(v);
    }
}

// ---------------- aggregation: one wave per node, bf16 in/out ----------------
__global__ __launch_bounds__(256) void agg_kernel(const int* __restrict__ off,
                                                  const int* __restrict__ packed,
                                                  const ushort* __restrict__ feat,
                                                  ushort* __restrict__ agg) {
    const int wid = (blockIdx.x * blockDim.x + threadIdx.x) >> 6;
    if (wid >= NN) return;
    const int lane = threadIdx.x & 63;
    const int s = off[wid], e = off[wid + 1];

    float2 a0{0,0},a1{0,0},a2{0,0},a3{0,0},a4{0,0},a5{0,0},a6{0,0},a7{0,0};
    int c0=0,c1=0,c2=0,c3=0,c4=0,c5=0,c6=0,c7=0;

    int p = (s < e) ? packed[s] : 0;
    for (int i = s; i < e; ++i) {
        int pn = (i + 1 < e) ? packed[i + 1] : 0;      // prefetch next
        const uint v = *reinterpret_cast<const uint*>(
            feat + (size_t)(p & 0xFFFF) * 128 + (lane << 1));
        const float fx = bflo(v), fy = bfhi(v);
        switch (p >> 16) {                              // wave-uniform, static reg indices
            case 0: a0.x+=fx; a0.y+=fy; ++c0; break;
            case 1: a1.x+=fx; a1.y+=fy; ++c1; break;
            case 2: a2.x+=fx; a2.y+=fy; ++c2; break;
            case 3: a3.x+=fx; a3.y+=fy; ++c3; break;
            case 4: a4.x+=fx; a4.y+=fy; ++c4; break;
            case 5: a5.x+=fx; a5.y+=fy; ++c5; break;
            case 6: a6.x+=fx; a6.y+=fy; ++c6; break;
            default: a7.x+=fx; a7.y+=fy; ++c7; break;
        }
        p = pn;
    }
    ushort* o = agg + (size_t)wid * 1024 + (lane << 1);
#define WR(r) { float inv = 1.0f / (float)((c##r > 0) ? c##r : 1); \
                uint w = (uint)f2bf(a##r.x * inv) | ((uint)f2bf(a##r.y * inv) << 16); \
                *reinterpret_cast<uint*>(o + (r) * 128) = w; }
    WR(0) WR(1) WR(2) WR(3) WR(4) WR(5) WR(6) WR(7)
#undef WR
}

// ---------------- MFMA GEMM: h = relu(bias + [xb|agg] @ Bt^T) ----------------
// A logical [N, 1152] bf16 (xb cols 0..127, agg cols 128..1151), Bt [128][1152] bf16.
// Block: 256 thr = 4 waves (2x2), tile 128(M) x 128(N), BK=64, mfma 32x32x16.
__global__ __launch_bounds__(256) void gemm_mfma(const ushort* __restrict__ xb,
                                                 const ushort* __restrict__ agg,
                                                 const ushort* __restrict__ Bt,
                                                 const float* __restrict__ bias,
                                                 ushort* __restrict__ hout) {
    __shared__ __align__(16) uint8_t smem[32768];   // As [128 rows][128B] | Bs [128][128B]
    const int t = threadIdx.x;
    const int lane = t & 63;
    const int w = t >> 6;
    const int wr = w >> 1, wc = w & 1;
    const int n0 = blockIdx.x * 128;
    const int l31 = lane & 31;
    const int lhalf = lane >> 5;

    f32x16 acc[2][2];
#pragma unroll
    for (int mi = 0; mi < 2; ++mi)
#pragma unroll
        for (int ni = 0; ni < 2; ++ni)
#pragma unroll
            for (int r = 0; r < 16; ++r) acc[mi][ni][r] = 0.f;

    // fragment read bases (XOR-swizzled LDS, swizzle = (row&7)<<4 on byte offset)
    int abase[2], aswz[2], bbase[2], bswz[2];
#pragma unroll
    for (int mi = 0; mi < 2; ++mi) {
        const int r = wr * 64 + mi * 32 + l31;
        abase[mi] = r * 128; aswz[mi] = (r & 7) << 4;
    }
#pragma unroll
    for (int ni = 0; ni < 2; ++ni) {
        const int n = wc * 64 + ni * 32 + l31;
        bbase[ni] = 16384 + n * 128; bswz[ni] = (n & 7) << 4;
    }
    const int ckb = lhalf << 4;   // lane's 16B slot within a 32B k-step

    // staging: thread handles 4 x 16B of A-tile and 4 x 16B of B-tile
    int srow[4], schk[4], awoff[4], bwoff[4], garow[4];
#pragma unroll
    for (int jj = 0; jj < 4; ++jj) {
        const int i = t + jj * 256;            // 0..1023
        srow[jj] = i >> 3;                     // 0..127
        schk[jj] = (i & 7) << 4;               // 0..112
        const int sw = schk[jj] ^ ((srow[jj] & 7) << 4);
        awoff[jj] = srow[jj] * 128 + sw;
        bwoff[jj] = 16384 + srow[jj] * 128 + sw;
        garow[jj] = min(n0 + srow[jj], NN - 1);   // clamp OOB rows (outputs discarded)
    }

#pragma unroll 1
    for (int kt = 0; kt < 18; ++kt) {
        const uint8_t* Asrc; size_t ldaB; int koffB;
        if (kt < 2) { Asrc = (const uint8_t*)xb;  ldaB = 256;  koffB = kt * 128; }
        else        { Asrc = (const uint8_t*)agg; ldaB = 2048; koffB = kt * 128 - 256; }
        uint4 ra[4], rb[4];
        const uint8_t* Bsrc = (const uint8_t*)Bt + kt * 128;
#pragma unroll
        for (int jj = 0; jj < 4; ++jj)
            ra[jj] = *reinterpret_cast<const uint4*>(Asrc + (size_t)garow[jj] * ldaB + koffB + schk[jj]);
#pragma unroll
        for (int jj = 0; jj < 4; ++jj)
            rb[jj] = *reinterpret_cast<const uint4*>(Bsrc + (size_t)srow[jj] * 2304 + schk[jj]);
        __syncthreads();   // previous tile's frag reads complete
#pragma unroll
        for (int jj = 0; jj < 4; ++jj) *reinterpret_cast<uint4*>(&smem[awoff[jj]]) = ra[jj];
#pragma unroll
        for (int jj = 0; jj < 4; ++jj) *reinterpret_cast<uint4*>(&smem[bwoff[jj]]) = rb[jj];
        __syncthreads();
#pragma unroll
        for (int kb = 0; kb < 4; ++kb) {
            const int cb = kb * 32 + ckb;
            bf16x8 af[2], bfr[2];
#pragma unroll
            for (int mi = 0; mi < 2; ++mi)
                af[mi] = *reinterpret_cast<const bf16x8*>(&smem[abase[mi] + (cb ^ aswz[mi])]);
#pragma unroll
            for (int ni = 0; ni < 2; ++ni)
                bfr[ni] = *reinterpret_cast<const bf16x8*>(&smem[bbase[ni] + (cb ^ bswz[ni])]);
#pragma unroll
            for (int mi = 0; mi < 2; ++mi)
#pragma unroll
                for (int ni = 0; ni < 2; ++ni)
                    acc[mi][ni] = __builtin_amdgcn_mfma_f32_32x32x16_bf16(
                        af[mi], bfr[ni], acc[mi][ni], 0, 0, 0);
        }
    }

    // epilogue: C/D layout (32x32): col = lane&31, row = (reg&3) + 8*(reg>>2) + 4*(lane>>5)
#pragma unroll
    for (int ni = 0; ni < 2; ++ni) {
        const int col = wc * 64 + ni * 32 + l31;
        const float bv = bias[col];
#pragma unroll
        for (int mi = 0; mi < 2; ++mi) {
#pragma unroll
            for (int reg = 0; reg < 16; ++reg) {
                const int row = n0 + wr * 64 + mi * 32 + 4 * lhalf + (reg & 3) + 8 * (reg >> 2);
                if (row < NN) {
                    const float v = fmaxf(acc[mi][ni][reg] + bv, 0.f);
                    hout[(size_t)row * 128 + col] = f2bf(v);
                }
            }
        }
    }
}

// ---------------- head: out[n] = h2[n] . Wout + bout ----------------
__global__ __launch_bounds__(256) void out_kernel(const ushort* __restrict__ h2,
                                                  const float* __restrict__ Wout,
                                                  const float* __restrict__ bout,
                                                  float* __restrict__ outp) {
    const int wid = (blockIdx.x * blockDim.x + threadIdx.x) >> 6;
    if (wid >= NN) return;
    const int lane = threadIdx.x & 63;
    const uint v = *reinterpret_cast<const uint*>(h2 + (size_t)wid * 128 + (lane << 1));
    const float2 ww = *reinterpret_cast<const float2*>(Wout + (lane << 1));
    float s = fmaf(bflo(v), ww.x, bfhi(v) * ww.y);
#pragma unroll
    for (int d = 32; d > 0; d >>= 1) s += __shfl_down(s, d, 64);
    if (lane == 0) outp[wid] = s + bout[0];
}

extern "C" void kernel_launch(void* const* d_in, const int* in_sizes, int n_in,
                              void* d_out, int out_size, void* d_ws, size_t ws_size,
                              hipStream_t stream) {
    const float* x     = (const float*)d_in[0];
    const int*   eidx  = (const int*)  d_in[1];
    const int*   etype = (const int*)  d_in[2];
    const float* W1    = (const float*)d_in[3];
    const float* root1 = (const float*)d_in[4];
    const float* b1    = (const float*)d_in[5];
    const float* W2    = (const float*)d_in[6];
    const float* root2 = (const float*)d_in[7];
    const float* b2    = (const float*)d_in[8];
    const float* Wout  = (const float*)d_in[9];
    const float* bout  = (const float*)d_in[10];
    float* out = (float*)d_out;

    const int* src = eidx;
    const int* dst = eidx + EE;

    char* ws = (char*)d_ws;
    size_t pos = 0;
    auto take = [&](size_t bytes) {
        char* p = ws + pos;
        pos = (pos + bytes + 255) & ~(size_t)255;
        return p;
    };
    int*    cnt    = (int*)   take((size_t)NN * 4);
    int*    off    = (int*)   take((size_t)(NN + 1) * 4);
    int*    cursor = (int*)   take((size_t)NN * 4);
    int*    packed = (int*)   take((size_t)EE * 4);
    ushort* xb     = (ushort*)take((size_t)NN * 128 * 2);
    ushort* h1     = (ushort*)take((size_t)NN * 128 * 2);
    ushort* h2     = (ushort*)take((size_t)NN * 128 * 2);
    ushort* agg    = (ushort*)take((size_t)NN * 1024 * 2);
    ushort* Bt1    = (ushort*)take((size_t)128 * 1152 * 2);
    ushort* Bt2    = (ushort*)take((size_t)128 * 1152 * 2);
    (void)ws_size; (void)n_in; (void)in_sizes; (void)out_size;

    const int eblocks = (EE + 255) / 256;           // 3125
    const int wblocks = (NN + 3) / 4;               // 12500 wave-per-node
    const int gblocks = (NN + 127) / 128;           // 391 GEMM tiles

    hipMemsetAsync(cnt, 0, (size_t)NN * 4, stream);
    hist_kernel   <<<eblocks, 256, 0, stream>>>(dst, cnt);
    scan_kernel   <<<1, 1024, 0, stream>>>(cnt, off, cursor);
    scatter_kernel<<<eblocks, 256, 0, stream>>>(src, dst, etype, cursor, packed);
    prep_w_kernel <<<dim3(128, 2), 256, 0, stream>>>(root1, W1, root2, W2, Bt1, Bt2);
    cvt_x_kernel  <<<3125, 256, 0, stream>>>(x, xb);

    // layer 1
    agg_kernel<<<wblocks, 256, 0, stream>>>(off, packed, xb, agg);
    gemm_mfma <<<gblocks, 256, 0, stream>>>(xb, agg, Bt1, b1, h1);
    // layer 2
    agg_kernel<<<wblocks, 256, 0, stream>>>(off, packed, h1, agg);
    gemm_mfma <<<gblocks, 256, 0, stream>>>(h1, agg, Bt2, b2, h2);
    // head
    out_kernel<<<wblocks, 256, 0, stream>>>(h2, Wout, bout, out);
}

// Round 3
// 420.680 us; speedup vs baseline: 2.2660x; 1.5216x over previous
//
#include <hip/hip_runtime.h>
#include <hip/hip_bf16.h>

// RGCN regression: N=50000, E=800000, R=8, C=H=128.
// Round 3: counting-sort edges by (dst*8+rel) -> branch-free relation-grouped
// aggregation (kills the 8-way switch that made agg VALU-bound at 86%).
//  1) hist over 400k (dst,rel) buckets; 3-kernel block scan; scatter src-only
//  2) cvt x -> bf16; weights -> Bt[n][k] bf16 (k = [root | W0..W7])
//  3) per layer: wave-per-node aggregation, static 8-group loop, bf16 in/out
//  4) per layer: MFMA GEMM  h = relu(bias + [xb|agg] @ Bt^T)  (32x32x16 bf16)
//  5) head: wave-per-node dot with Wout

constexpr int NN = 50000;
constexpr int EE = 800000;
constexpr int NB = NN * 8;          // 400000 (dst,rel) buckets

typedef __attribute__((ext_vector_type(8))) short bf16x8;
typedef __attribute__((ext_vector_type(16))) float f32x16;

static __device__ __forceinline__ ushort f2bf(float f) {
    uint u = __float_as_uint(f);
    uint r = (u + 0x7fffu + ((u >> 16) & 1u)) >> 16;   // RTNE
    return (ushort)r;
}
static __device__ __forceinline__ float bflo(uint v) { return __uint_as_float(v << 16); }
static __device__ __forceinline__ float bfhi(uint v) { return __uint_as_float(v & 0xffff0000u); }

// ---------------- histogram over (dst*8+rel) ----------------
__global__ void hist_kernel(const int* __restrict__ dst, const int* __restrict__ et,
                            int* __restrict__ cnt) {
    int e = blockIdx.x * blockDim.x + threadIdx.x;
    if (e < EE) atomicAdd(&cnt[dst[e] * 8 + et[e]], 1);
}

// ---------------- 3-kernel exclusive scan over NB counts ----------------
__global__ __launch_bounds__(1024) void scan1_kernel(const int* __restrict__ cnt,
                                                     int* __restrict__ part,
                                                     int* __restrict__ bsum) {
    __shared__ int sm[1024];
    const int t = threadIdx.x;
    const int g = blockIdx.x * 1024 + t;
    const int v = (g < NB) ? cnt[g] : 0;
    sm[t] = v;
    __syncthreads();
    for (int d = 1; d < 1024; d <<= 1) {
        int u = (t >= d) ? sm[t - d] : 0;
        __syncthreads();
        sm[t] += u;
        __syncthreads();
    }
    if (g < NB) part[g] = sm[t] - v;             // exclusive within block
    if (t == 1023) bsum[blockIdx.x] = sm[1023];  // block total
}

__global__ __launch_bounds__(512) void scan2_kernel(int* __restrict__ bsum, int nblk) {
    __shared__ int sm[512];
    const int t = threadIdx.x;
    const int v = (t < nblk) ? bsum[t] : 0;
    sm[t] = v;
    __syncthreads();
    for (int d = 1; d < 512; d <<= 1) {
        int u = (t >= d) ? sm[t - d] : 0;
        __syncthreads();
        sm[t] += u;
        __syncthreads();
    }
    if (t < nblk) bsum[t] = sm[t] - v;           // exclusive block offsets
}

__global__ __launch_bounds__(1024) void scan3_kernel(const int* __restrict__ part,
                                                     const int* __restrict__ bsum,
                                                     int* __restrict__ off,
                                                     int* __restrict__ cursor) {
    const int g = blockIdx.x * 1024 + threadIdx.x;
    if (g < NB) {
        const int v = part[g] + bsum[blockIdx.x];
        off[g] = v;
        cursor[g] = v;
    }
    if (g == NB) off[NB] = EE;
}

// ---------------- scatter: srcs sorted by (dst,rel) ----------------
__global__ void scatter_kernel(const int* __restrict__ src, const int* __restrict__ dst,
                               const int* __restrict__ et, int* __restrict__ cursor,
                               int* __restrict__ srcs) {
    int e = blockIdx.x * blockDim.x + threadIdx.x;
    if (e < EE) {
        const int b = dst[e] * 8 + et[e];
        const int pos = atomicAdd(&cursor[b], 1);
        srcs[pos] = src[e];
    }
}

// ---------------- x fp32 -> bf16 ----------------
__global__ __launch_bounds__(256) void cvt_x_kernel(const float* __restrict__ x,
                                                    ushort* __restrict__ xb) {
    const int tid = blockIdx.x * blockDim.x + threadIdx.x;   // 800000 threads, 8 elems each
    const size_t i = (size_t)tid * 8;
    const float4 v0 = *reinterpret_cast<const float4*>(x + i);
    const float4 v1 = *reinterpret_cast<const float4*>(x + i + 4);
    uint4 o;
    o.x = (uint)f2bf(v0.x) | ((uint)f2bf(v0.y) << 16);
    o.y = (uint)f2bf(v0.z) | ((uint)f2bf(v0.w) << 16);
    o.z = (uint)f2bf(v1.x) | ((uint)f2bf(v1.y) << 16);
    o.w = (uint)f2bf(v1.z) | ((uint)f2bf(v1.w) << 16);
    *reinterpret_cast<uint4*>(xb + i) = o;
}

// ---------------- weights -> Bt[n][k] bf16, k = [root(128) | W(1024)] ----------------
__global__ __launch_bounds__(256) void prep_w_kernel(const float* __restrict__ root1,
                                                     const float* __restrict__ W1,
                                                     const float* __restrict__ root2,
                                                     const float* __restrict__ W2,
                                                     ushort* __restrict__ Bt1,
                                                     ushort* __restrict__ Bt2) {
    const float* root = blockIdx.y ? root2 : root1;
    const float* W    = blockIdx.y ? W2 : W1;
    ushort* Bt        = blockIdx.y ? Bt2 : Bt1;
    const int n = blockIdx.x;                       // 0..127 output col
    for (int k = threadIdx.x; k < 1152; k += 256) {
        float v = (k < 128) ? root[(size_t)k * 128 + n]
                            : W[(size_t)(k - 128) * 128 + n];
        Bt[(size_t)n * 1152 + k] = f2bf(v);
    }
}

// ---------------- aggregation: one wave per node, relation-grouped ----------------
__global__ __launch_bounds__(256) void agg_kernel(const int* __restrict__ off,
                                                  const int* __restrict__ srcs,
                                                  const ushort* __restrict__ feat,
                                                  ushort* __restrict__ agg) {
    int wid = (blockIdx.x * blockDim.x + threadIdx.x) >> 6;
    if (wid >= NN) return;
    wid = __builtin_amdgcn_readfirstlane(wid);      // promote to SGPR (uniform anyway)
    const int lane = threadIdx.x & 63;

    int offs[9];
#pragma unroll
    for (int r = 0; r < 9; ++r) offs[r] = off[wid * 8 + r];

    ushort* o = agg + (size_t)wid * 1024 + (lane << 1);
#pragma unroll
    for (int r = 0; r < 8; ++r) {
        const int s = offs[r], e = offs[r + 1];
        float ax = 0.f, ay = 0.f;
        int p = (s < e) ? srcs[s] : 0;
        for (int i = s; i < e; ++i) {
            const int pn = (i + 1 < e) ? srcs[i + 1] : 0;   // prefetch next src
            const uint v = *reinterpret_cast<const uint*>(
                feat + (size_t)p * 128 + (lane << 1));
            ax += bflo(v); ay += bfhi(v);
            p = pn;
        }
        const float inv = 1.0f / (float)max(e - s, 1);
        const uint wv = (uint)f2bf(ax * inv) | ((uint)f2bf(ay * inv) << 16);
        *reinterpret_cast<uint*>(o + r * 128) = wv;
    }
}

// ---------------- MFMA GEMM: h = relu(bias + [xb|agg] @ Bt^T) ----------------
// A logical [N, 1152] bf16 (xb cols 0..127, agg cols 128..1151), Bt [128][1152] bf16.
// Block: 256 thr = 4 waves (2x2), tile 128(M) x 128(N), BK=64, mfma 32x32x16.
__global__ __launch_bounds__(256) void gemm_mfma(const ushort* __restrict__ xb,
                                                 const ushort* __restrict__ agg,
                                                 const ushort* __restrict__ Bt,
                                                 const float* __restrict__ bias,
                                                 ushort* __restrict__ hout) {
    __shared__ __align__(16) uint8_t smem[32768];   // As [128 rows][128B] | Bs [128][128B]
    const int t = threadIdx.x;
    const int lane = t & 63;
    const int w = t >> 6;
    const int wr = w >> 1, wc = w & 1;
    const int n0 = blockIdx.x * 128;
    const int l31 = lane & 31;
    const int lhalf = lane >> 5;

    f32x16 acc[2][2];
#pragma unroll
    for (int mi = 0; mi < 2; ++mi)
#pragma unroll
        for (int ni = 0; ni < 2; ++ni)
#pragma unroll
            for (int r = 0; r < 16; ++r) acc[mi][ni][r] = 0.f;

    // fragment read bases (XOR-swizzled LDS, swizzle = (row&7)<<4 on byte offset)
    int abase[2], aswz[2], bbase[2], bswz[2];
#pragma unroll
    for (int mi = 0; mi < 2; ++mi) {
        const int r = wr * 64 + mi * 32 + l31;
        abase[mi] = r * 128; aswz[mi] = (r & 7) << 4;
    }
#pragma unroll
    for (int ni = 0; ni < 2; ++ni) {
        const int n = wc * 64 + ni * 32 + l31;
        bbase[ni] = 16384 + n * 128; bswz[ni] = (n & 7) << 4;
    }
    const int ckb = lhalf << 4;   // lane's 16B slot within a 32B k-step

    // staging: thread handles 4 x 16B of A-tile and 4 x 16B of B-tile
    int srow[4], schk[4], awoff[4], bwoff[4], garow[4];
#pragma unroll
    for (int jj = 0; jj < 4; ++jj) {
        const int i = t + jj * 256;            // 0..1023
        srow[jj] = i >> 3;                     // 0..127
        schk[jj] = (i & 7) << 4;               // 0..112
        const int sw = schk[jj] ^ ((srow[jj] & 7) << 4);
        awoff[jj] = srow[jj] * 128 + sw;
        bwoff[jj] = 16384 + srow[jj] * 128 + sw;
        garow[jj] = min(n0 + srow[jj], NN - 1);   // clamp OOB rows (outputs discarded)
    }

#pragma unroll 1
    for (int kt = 0; kt < 18; ++kt) {
        const uint8_t* Asrc; size_t ldaB; int koffB;
        if (kt < 2) { Asrc = (const uint8_t*)xb;  ldaB = 256;  koffB = kt * 128; }
        else        { Asrc = (const uint8_t*)agg; ldaB = 2048; koffB = kt * 128 - 256; }
        uint4 ra[4], rb[4];
        const uint8_t* Bsrc = (const uint8_t*)Bt + kt * 128;
#pragma unroll
        for (int jj = 0; jj < 4; ++jj)
            ra[jj] = *reinterpret_cast<const uint4*>(Asrc + (size_t)garow[jj] * ldaB + koffB + schk[jj]);
#pragma unroll
        for (int jj = 0; jj < 4; ++jj)
            rb[jj] = *reinterpret_cast<const uint4*>(Bsrc + (size_t)srow[jj] * 2304 + schk[jj]);
        __syncthreads();   // previous tile's frag reads complete
#pragma unroll
        for (int jj = 0; jj < 4; ++jj) *reinterpret_cast<uint4*>(&smem[awoff[jj]]) = ra[jj];
#pragma unroll
        for (int jj = 0; jj < 4; ++jj) *reinterpret_cast<uint4*>(&smem[bwoff[jj]]) = rb[jj];
        __syncthreads();
#pragma unroll
        for (int kb = 0; kb < 4; ++kb) {
            const int cb = kb * 32 + ckb;
            bf16x8 af[2], bfr[2];
#pragma unroll
            for (int mi = 0; mi < 2; ++mi)
                af[mi] = *reinterpret_cast<const bf16x8*>(&smem[abase[mi] + (cb ^ aswz[mi])]);
#pragma unroll
            for (int ni = 0; ni < 2; ++ni)
                bfr[ni] = *reinterpret_cast<const bf16x8*>(&smem[bbase[ni] + (cb ^ bswz[ni])]);
#pragma unroll
            for (int mi = 0; mi < 2; ++mi)
#pragma unroll
                for (int ni = 0; ni < 2; ++ni)
                    acc[mi][ni] = __builtin_amdgcn_mfma_f32_32x32x16_bf16(
                        af[mi], bfr[ni], acc[mi][ni], 0, 0, 0);
        }
    }

    // epilogue: C/D layout (32x32): col = lane&31, row = (reg&3) + 8*(reg>>2) + 4*(lane>>5)
#pragma unroll
    for (int ni = 0; ni < 2; ++ni) {
        const int col = wc * 64 + ni * 32 + l31;
        const float bv = bias[col];
#pragma unroll
        for (int mi = 0; mi < 2; ++mi) {
#pragma unroll
            for (int reg = 0; reg < 16; ++reg) {
                const int row = n0 + wr * 64 + mi * 32 + 4 * lhalf + (reg & 3) + 8 * (reg >> 2);
                if (row < NN) {
                    const float v = fmaxf(acc[mi][ni][reg] + bv, 0.f);
                    hout[(size_t)row * 128 + col] = f2bf(v);
                }
            }
        }
    }
}

// ---------------- head: out[n] = h2[n] . Wout + bout ----------------
__global__ __launch_bounds__(256) void out_kernel(const ushort* __restrict__ h2,
                                                  const float* __restrict__ Wout,
                                                  const float* __restrict__ bout,
                                                  float* __restrict__ outp) {
    const int wid = (blockIdx.x * blockDim.x + threadIdx.x) >> 6;
    if (wid >= NN) return;
    const int lane = threadIdx.x & 63;
    const uint v = *reinterpret_cast<const uint*>(h2 + (size_t)wid * 128 + (lane << 1));
    const float2 ww = *reinterpret_cast<const float2*>(Wout + (lane << 1));
    float s = fmaf(bflo(v), ww.x, bfhi(v) * ww.y);
#pragma unroll
    for (int d = 32; d > 0; d >>= 1) s += __shfl_down(s, d, 64);
    if (lane == 0) outp[wid] = s + bout[0];
}

extern "C" void kernel_launch(void* const* d_in, const int* in_sizes, int n_in,
                              void* d_out, int out_size, void* d_ws, size_t ws_size,
                              hipStream_t stream) {
    const float* x     = (const float*)d_in[0];
    const int*   eidx  = (const int*)  d_in[1];
    const int*   etype = (const int*)  d_in[2];
    const float* W1    = (const float*)d_in[3];
    const float* root1 = (const float*)d_in[4];
    const float* b1    = (const float*)d_in[5];
    const float* W2    = (const float*)d_in[6];
    const float* root2 = (const float*)d_in[7];
    const float* b2    = (const float*)d_in[8];
    const float* Wout  = (const float*)d_in[9];
    const float* bout  = (const float*)d_in[10];
    float* out = (float*)d_out;

    const int* src = eidx;
    const int* dst = eidx + EE;

    char* ws = (char*)d_ws;
    size_t pos = 0;
    auto take = [&](size_t bytes) {
        char* p = ws + pos;
        pos = (pos + bytes + 255) & ~(size_t)255;
        return p;
    };
    int*    cnt    = (int*)   take((size_t)NB * 4);
    int*    off    = (int*)   take((size_t)(NB + 1) * 4);
    int*    cursor = (int*)   take((size_t)NB * 4);
    int*    part   = (int*)   take((size_t)NB * 4);
    int*    bsum   = (int*)   take((size_t)512 * 4);
    int*    srcs   = (int*)   take((size_t)EE * 4);
    ushort* xb     = (ushort*)take((size_t)NN * 128 * 2);
    ushort* h1     = (ushort*)take((size_t)NN * 128 * 2);
    ushort* h2     = (ushort*)take((size_t)NN * 128 * 2);
    ushort* agg    = (ushort*)take((size_t)NN * 1024 * 2);
    ushort* Bt1    = (ushort*)take((size_t)128 * 1152 * 2);
    ushort* Bt2    = (ushort*)take((size_t)128 * 1152 * 2);
    (void)ws_size; (void)n_in; (void)in_sizes; (void)out_size;

    const int eblocks = (EE + 255) / 256;           // 3125
    const int sblocks = (NB + 1023) / 1024;         // 391 scan blocks
    const int wblocks = (NN + 3) / 4;               // 12500 wave-per-node
    const int gblocks = (NN + 127) / 128;           // 391 GEMM tiles

    hipMemsetAsync(cnt, 0, (size_t)NB * 4, stream);
    hist_kernel   <<<eblocks, 256, 0, stream>>>(dst, etype, cnt);
    scan1_kernel  <<<sblocks, 1024, 0, stream>>>(cnt, part, bsum);
    scan2_kernel  <<<1, 512, 0, stream>>>(bsum, sblocks);
    scan3_kernel  <<<sblocks, 1024, 0, stream>>>(part, bsum, off, cursor);
    scatter_kernel<<<eblocks, 256, 0, stream>>>(src, dst, etype, cursor, srcs);
    prep_w_kernel <<<dim3(128, 2), 256, 0, stream>>>(root1, W1, root2, W2, Bt1, Bt2);
    cvt_x_kernel  <<<3125, 256, 0, stream>>>(x, xb);

    // layer 1
    agg_kernel<<<wblocks, 256, 0, stream>>>(off, srcs, xb, agg);
    gemm_mfma <<<gblocks, 256, 0, stream>>>(xb, agg, Bt1, b1, h1);
    // layer 2
    agg_kernel<<<wblocks, 256, 0, stream>>>(off, srcs, h1, agg);
    gemm_mfma <<<gblocks, 256, 0, stream>>>(h1, agg, Bt2, b2, h2);
    // head
    out_kernel<<<wblocks, 256, 0, stream>>>(h2, Wout, bout, out);
}

// Round 4
// 305.325 us; speedup vs baseline: 3.1221x; 1.3778x over previous
//
#include <hip/hip_runtime.h>
#include <hip/hip_bf16.h>

// RGCN regression: N=50000, E=800000, R=8, C=H=128.
// Round 4: GEMM restructure (the R3 bottleneck: 100us, MfmaUtil 5.6%, occupancy 14%).
//  - 64x128 tile -> 782 blocks (~3 blocks/CU vs 1.5)
//  - global_load_lds width=16 direct staging (pre-swizzled global source,
//    linear LDS dest, XOR-swizzled ds_read: both-sides-or-neither)
//  - 2-phase double-buffer prefetch: STAGE(next) || COMPUTE(cur), 1 barrier/tile
// Everything else (sort, agg, head) unchanged from R3.

constexpr int NN = 50000;
constexpr int EE = 800000;
constexpr int NB = NN * 8;          // 400000 (dst,rel) buckets

typedef __attribute__((ext_vector_type(8))) short bf16x8;
typedef __attribute__((ext_vector_type(16))) float f32x16;
typedef __attribute__((address_space(3))) uint32_t lds_u32;
typedef __attribute__((address_space(1))) const uint32_t glb_u32;

static __device__ __forceinline__ ushort f2bf(float f) {
    uint u = __float_as_uint(f);
    uint r = (u + 0x7fffu + ((u >> 16) & 1u)) >> 16;   // RTNE
    return (ushort)r;
}
static __device__ __forceinline__ float bflo(uint v) { return __uint_as_float(v << 16); }
static __device__ __forceinline__ float bfhi(uint v) { return __uint_as_float(v & 0xffff0000u); }

static __device__ __forceinline__ void stage16(const void* g, void* lds) {
    __builtin_amdgcn_global_load_lds((glb_u32*)g, (lds_u32*)lds, 16, 0, 0);
}

// ---------------- histogram over (dst*8+rel) ----------------
__global__ void hist_kernel(const int* __restrict__ dst, const int* __restrict__ et,
                            int* __restrict__ cnt) {
    int e = blockIdx.x * blockDim.x + threadIdx.x;
    if (e < EE) atomicAdd(&cnt[dst[e] * 8 + et[e]], 1);
}

// ---------------- 3-kernel exclusive scan over NB counts ----------------
__global__ __launch_bounds__(1024) void scan1_kernel(const int* __restrict__ cnt,
                                                     int* __restrict__ part,
                                                     int* __restrict__ bsum) {
    __shared__ int sm[1024];
    const int t = threadIdx.x;
    const int g = blockIdx.x * 1024 + t;
    const int v = (g < NB) ? cnt[g] : 0;
    sm[t] = v;
    __syncthreads();
    for (int d = 1; d < 1024; d <<= 1) {
        int u = (t >= d) ? sm[t - d] : 0;
        __syncthreads();
        sm[t] += u;
        __syncthreads();
    }
    if (g < NB) part[g] = sm[t] - v;             // exclusive within block
    if (t == 1023) bsum[blockIdx.x] = sm[1023];  // block total
}

__global__ __launch_bounds__(512) void scan2_kernel(int* __restrict__ bsum, int nblk) {
    __shared__ int sm[512];
    const int t = threadIdx.x;
    const int v = (t < nblk) ? bsum[t] : 0;
    sm[t] = v;
    __syncthreads();
    for (int d = 1; d < 512; d <<= 1) {
        int u = (t >= d) ? sm[t - d] : 0;
        __syncthreads();
        sm[t] += u;
        __syncthreads();
    }
    if (t < nblk) bsum[t] = sm[t] - v;           // exclusive block offsets
}

__global__ __launch_bounds__(1024) void scan3_kernel(const int* __restrict__ part,
                                                     const int* __restrict__ bsum,
                                                     int* __restrict__ off,
                                                     int* __restrict__ cursor) {
    const int g = blockIdx.x * 1024 + threadIdx.x;
    if (g < NB) {
        const int v = part[g] + bsum[blockIdx.x];
        off[g] = v;
        cursor[g] = v;
    }
    if (g == NB) off[NB] = EE;
}

// ---------------- scatter: srcs sorted by (dst,rel) ----------------
__global__ void scatter_kernel(const int* __restrict__ src, const int* __restrict__ dst,
                               const int* __restrict__ et, int* __restrict__ cursor,
                               int* __restrict__ srcs) {
    int e = blockIdx.x * blockDim.x + threadIdx.x;
    if (e < EE) {
        const int b = dst[e] * 8 + et[e];
        const int pos = atomicAdd(&cursor[b], 1);
        srcs[pos] = src[e];
    }
}

// ---------------- x fp32 -> bf16 ----------------
__global__ __launch_bounds__(256) void cvt_x_kernel(const float* __restrict__ x,
                                                    ushort* __restrict__ xb) {
    const int tid = blockIdx.x * blockDim.x + threadIdx.x;   // 800000 threads, 8 elems each
    const size_t i = (size_t)tid * 8;
    const float4 v0 = *reinterpret_cast<const float4*>(x + i);
    const float4 v1 = *reinterpret_cast<const float4*>(x + i + 4);
    uint4 o;
    o.x = (uint)f2bf(v0.x) | ((uint)f2bf(v0.y) << 16);
    o.y = (uint)f2bf(v0.z) | ((uint)f2bf(v0.w) << 16);
    o.z = (uint)f2bf(v1.x) | ((uint)f2bf(v1.y) << 16);
    o.w = (uint)f2bf(v1.z) | ((uint)f2bf(v1.w) << 16);
    *reinterpret_cast<uint4*>(xb + i) = o;
}

// ---------------- weights -> Bt[n][k] bf16, k = [root(128) | W(1024)] ----------------
__global__ __launch_bounds__(256) void prep_w_kernel(const float* __restrict__ root1,
                                                     const float* __restrict__ W1,
                                                     const float* __restrict__ root2,
                                                     const float* __restrict__ W2,
                                                     ushort* __restrict__ Bt1,
                                                     ushort* __restrict__ Bt2) {
    const float* root = blockIdx.y ? root2 : root1;
    const float* W    = blockIdx.y ? W2 : W1;
    ushort* Bt        = blockIdx.y ? Bt2 : Bt1;
    const int n = blockIdx.x;                       // 0..127 output col
    for (int k = threadIdx.x; k < 1152; k += 256) {
        float v = (k < 128) ? root[(size_t)k * 128 + n]
                            : W[(size_t)(k - 128) * 128 + n];
        Bt[(size_t)n * 1152 + k] = f2bf(v);
    }
}

// ---------------- aggregation: one wave per node, relation-grouped ----------------
__global__ __launch_bounds__(256) void agg_kernel(const int* __restrict__ off,
                                                  const int* __restrict__ srcs,
                                                  const ushort* __restrict__ feat,
                                                  ushort* __restrict__ agg) {
    int wid = (blockIdx.x * blockDim.x + threadIdx.x) >> 6;
    if (wid >= NN) return;
    wid = __builtin_amdgcn_readfirstlane(wid);      // promote to SGPR (uniform anyway)
    const int lane = threadIdx.x & 63;

    int offs[9];
#pragma unroll
    for (int r = 0; r < 9; ++r) offs[r] = off[wid * 8 + r];

    ushort* o = agg + (size_t)wid * 1024 + (lane << 1);
#pragma unroll
    for (int r = 0; r < 8; ++r) {
        const int s = offs[r], e = offs[r + 1];
        float ax = 0.f, ay = 0.f;
        int p = (s < e) ? srcs[s] : 0;
        for (int i = s; i < e; ++i) {
            const int pn = (i + 1 < e) ? srcs[i + 1] : 0;   // prefetch next src
            const uint v = *reinterpret_cast<const uint*>(
                feat + (size_t)p * 128 + (lane << 1));
            ax += bflo(v); ay += bfhi(v);
            p = pn;
        }
        const float inv = 1.0f / (float)max(e - s, 1);
        const uint wv = (uint)f2bf(ax * inv) | ((uint)f2bf(ay * inv) << 16);
        *reinterpret_cast<uint*>(o + r * 128) = wv;
    }
}

// ---------------- MFMA GEMM: h = relu(bias + [xb|agg] @ Bt^T) ----------------
// A logical [N, 1152] bf16 (xb cols 0..127, agg cols 128..1151), Bt [128][1152] bf16.
// Block: 256 thr = 4 waves (2x2), tile 64(M) x 128(N), BK=64, mfma 32x32x16.
// Double-buffered LDS: buf = [A 64x128B (8KB) | B 128x128B (16KB)] x 2 = 48KB.
// LDS is written LINEARLY by global_load_lds; the XOR swizzle ((row&7)<<4) is
// applied on the per-lane GLOBAL source chunk and again on the ds_read side.
__global__ __launch_bounds__(256) void gemm_mfma(const ushort* __restrict__ xb,
                                                 const ushort* __restrict__ agg,
                                                 const ushort* __restrict__ Bt,
                                                 const float* __restrict__ bias,
                                                 ushort* __restrict__ hout) {
    __shared__ __align__(16) uint8_t smem[49152];
    const int t = threadIdx.x;
    const int lane = t & 63;
    const int w = t >> 6;                 // wave 0..3
    const int wr = w >> 1, wc = w & 1;    // 2(M) x 2(N) wave grid
    const int n0 = blockIdx.x * 64;
    const int l31 = lane & 31;
    const int lhalf = lane >> 5;

    f32x16 acc0, acc1;
#pragma unroll
    for (int r = 0; r < 16; ++r) { acc0[r] = 0.f; acc1[r] = 0.f; }

    // fragment read offsets (byte), swizzle = (row&7)<<4
    const int rA = wr * 32 + l31;
    const int aoff = rA * 128, aswz = (rA & 7) << 4;
    const int nB0 = wc * 64 + l31;
    const int nB1 = nB0 + 32;
    const int boff0 = 8192 + nB0 * 128, bswz0 = (nB0 & 7) << 4;
    const int boff1 = 8192 + nB1 * 128, bswz1 = (nB1 & 7) << 4;
    const int ckb = lhalf << 4;           // lane's 16B slot within a 32B k-step

    // staging: per tile, wave w issues 2 A-loads (rows 16w..16w+15) and
    // 4 B-loads (rows 32w..32w+31); each gload_lds = 64 lanes x 16B = 8 rows.
    const int rsub = lane >> 3;                                   // 0..7 row within inst
    const int srcChunk = (((lane & 7) ^ (lane >> 3)) << 4);       // pre-swizzled source chunk
    int garowA[2];
#pragma unroll
    for (int jj = 0; jj < 2; ++jj)
        garowA[jj] = min(n0 + 16 * w + 8 * jj + rsub, NN - 1);    // clamp OOB rows
    size_t bOffG[4];
#pragma unroll
    for (int jj = 0; jj < 4; ++jj)
        bOffG[jj] = (size_t)(32 * w + 8 * jj + rsub) * 2304 + srcChunk;

    const uint8_t* xb8  = (const uint8_t*)xb;
    const uint8_t* agg8 = (const uint8_t*)agg;
    const uint8_t* Bt8  = (const uint8_t*)Bt;

    auto STAGE = [&](int buf, int kt) {
        uint8_t* base = smem + buf * 24576;
        const uint8_t* Asrc; int shift, koffB;
        if (kt < 2) { Asrc = xb8;  shift = 8;  koffB = kt * 128; }          // row=256B
        else        { Asrc = agg8; shift = 11; koffB = (kt - 2) * 128; }    // row=2048B
#pragma unroll
        for (int jj = 0; jj < 2; ++jj)
            stage16(Asrc + (((size_t)garowA[jj]) << shift) + koffB + srcChunk,
                    base + (2 * w + jj) * 1024);
#pragma unroll
        for (int jj = 0; jj < 4; ++jj)
            stage16(Bt8 + bOffG[jj] + kt * 128,
                    base + 8192 + (4 * w + jj) * 1024);
    };

    auto COMPUTE = [&](int buf) {
        const uint8_t* base = smem + buf * 24576;
#pragma unroll
        for (int kb = 0; kb < 4; ++kb) {
            const int cb = kb * 32 + ckb;
            const bf16x8 af = *reinterpret_cast<const bf16x8*>(base + aoff  + (cb ^ aswz));
            const bf16x8 b0 = *reinterpret_cast<const bf16x8*>(base + boff0 + (cb ^ bswz0));
            const bf16x8 b1 = *reinterpret_cast<const bf16x8*>(base + boff1 + (cb ^ bswz1));
            acc0 = __builtin_amdgcn_mfma_f32_32x32x16_bf16(af, b0, acc0, 0, 0, 0);
            acc1 = __builtin_amdgcn_mfma_f32_32x32x16_bf16(af, b1, acc1, 0, 0, 0);
        }
    };

    STAGE(0, 0);
    __syncthreads();                       // implicit vmcnt(0) drain: buf0 ready
    int cur = 0;
#pragma unroll 1
    for (int kt = 0; kt < 17; ++kt) {
        STAGE(cur ^ 1, kt + 1);            // async loads fly under COMPUTE
        COMPUTE(cur);
        __syncthreads();                   // drains vmcnt+lgkmcnt: next buf ready, reads done
        cur ^= 1;
    }
    COMPUTE(cur);

    // epilogue: 32x32 C/D layout: col = lane&31, row = (reg&3)+8*(reg>>2)+4*(lane>>5)
#pragma unroll
    for (int ni = 0; ni < 2; ++ni) {
        const int col = wc * 64 + ni * 32 + l31;
        const float bv = bias[col];
        const f32x16& a = ni ? acc1 : acc0;
#pragma unroll
        for (int reg = 0; reg < 16; ++reg) {
            const int row = n0 + wr * 32 + 4 * lhalf + (reg & 3) + 8 * (reg >> 2);
            if (row < NN) {
                const float v = fmaxf(a[reg] + bv, 0.f);
                hout[(size_t)row * 128 + col] = f2bf(v);
            }
        }
    }
}

// ---------------- head: out[n] = h2[n] . Wout + bout ----------------
__global__ __launch_bounds__(256) void out_kernel(const ushort* __restrict__ h2,
                                                  const float* __restrict__ Wout,
                                                  const float* __restrict__ bout,
                                                  float* __restrict__ outp) {
    const int wid = (blockIdx.x * blockDim.x + threadIdx.x) >> 6;
    if (wid >= NN) return;
    const int lane = threadIdx.x & 63;
    const uint v = *reinterpret_cast<const uint*>(h2 + (size_t)wid * 128 + (lane << 1));
    const float2 ww = *reinterpret_cast<const float2*>(Wout + (lane << 1));
    float s = fmaf(bflo(v), ww.x, bfhi(v) * ww.y);
#pragma unroll
    for (int d = 32; d > 0; d >>= 1) s += __shfl_down(s, d, 64);
    if (lane == 0) outp[wid] = s + bout[0];
}

extern "C" void kernel_launch(void* const* d_in, const int* in_sizes, int n_in,
                              void* d_out, int out_size, void* d_ws, size_t ws_size,
                              hipStream_t stream) {
    const float* x     = (const float*)d_in[0];
    const int*   eidx  = (const int*)  d_in[1];
    const int*   etype = (const int*)  d_in[2];
    const float* W1    = (const float*)d_in[3];
    const float* root1 = (const float*)d_in[4];
    const float* b1    = (const float*)d_in[5];
    const float* W2    = (const float*)d_in[6];
    const float* root2 = (const float*)d_in[7];
    const float* b2    = (const float*)d_in[8];
    const float* Wout  = (const float*)d_in[9];
    const float* bout  = (const float*)d_in[10];
    float* out = (float*)d_out;

    const int* src = eidx;
    const int* dst = eidx + EE;

    char* ws = (char*)d_ws;
    size_t pos = 0;
    auto take = [&](size_t bytes) {
        char* p = ws + pos;
        pos = (pos + bytes + 255) & ~(size_t)255;
        return p;
    };
    int*    cnt    = (int*)   take((size_t)NB * 4);
    int*    off    = (int*)   take((size_t)(NB + 1) * 4);
    int*    cursor = (int*)   take((size_t)NB * 4);
    int*    part   = (int*)   take((size_t)NB * 4);
    int*    bsum   = (int*)   take((size_t)512 * 4);
    int*    srcs   = (int*)   take((size_t)EE * 4);
    ushort* xb     = (ushort*)take((size_t)NN * 128 * 2);
    ushort* h1     = (ushort*)take((size_t)NN * 128 * 2);
    ushort* h2     = (ushort*)take((size_t)NN * 128 * 2);
    ushort* agg    = (ushort*)take((size_t)NN * 1024 * 2);
    ushort* Bt1    = (ushort*)take((size_t)128 * 1152 * 2);
    ushort* Bt2    = (ushort*)take((size_t)128 * 1152 * 2);
    (void)ws_size; (void)n_in; (void)in_sizes; (void)out_size;

    const int eblocks = (EE + 255) / 256;           // 3125
    const int sblocks = (NB + 1023) / 1024;         // 391 scan blocks
    const int wblocks = (NN + 3) / 4;               // 12500 wave-per-node
    const int gblocks = (NN + 63) / 64;             // 782 GEMM tiles

    hipMemsetAsync(cnt, 0, (size_t)NB * 4, stream);
    hist_kernel   <<<eblocks, 256, 0, stream>>>(dst, etype, cnt);
    scan1_kernel  <<<sblocks, 1024, 0, stream>>>(cnt, part, bsum);
    scan2_kernel  <<<1, 512, 0, stream>>>(bsum, sblocks);
    scan3_kernel  <<<sblocks, 1024, 0, stream>>>(part, bsum, off, cursor);
    scatter_kernel<<<eblocks, 256, 0, stream>>>(src, dst, etype, cursor, srcs);
    prep_w_kernel <<<dim3(128, 2), 256, 0, stream>>>(root1, W1, root2, W2, Bt1, Bt2);
    cvt_x_kernel  <<<3125, 256, 0, stream>>>(x, xb);

    // layer 1
    agg_kernel<<<wblocks, 256, 0, stream>>>(off, srcs, xb, agg);
    gemm_mfma <<<gblocks, 256, 0, stream>>>(xb, agg, Bt1, b1, h1);
    // layer 2
    agg_kernel<<<wblocks, 256, 0, stream>>>(off, srcs, h1, agg);
    gemm_mfma <<<gblocks, 256, 0, stream>>>(h1, agg, Bt2, b2, h2);
    // head
    out_kernel<<<wblocks, 256, 0, stream>>>(h2, Wout, bout, out);
}

// Round 5
// 276.917 us; speedup vs baseline: 3.4424x; 1.1026x over previous
//
#include <hip/hip_runtime.h>
#include <hip/hip_bf16.h>

// RGCN regression: N=50000, E=800000, R=8, C=H=128.
// Round 5: agg restructure (R4 bottleneck: 2x61.8us, latency-bound serial gather).
//  - wave = 8 relation-groups x 8 lanes; all 8 segments of a node gathered
//    CONCURRENTLY (serial depth max_r cnt_r instead of sum_r cnt_r, ~3x less)
//  - lane owns 32B of the 256B row -> 16 fp32 accums, no cross-lane combines
// Sort, GEMM (R4 structure), head unchanged.

constexpr int NN = 50000;
constexpr int EE = 800000;
constexpr int NB = NN * 8;          // 400000 (dst,rel) buckets

typedef __attribute__((ext_vector_type(8))) short bf16x8;
typedef __attribute__((ext_vector_type(16))) float f32x16;
typedef __attribute__((address_space(3))) uint32_t lds_u32;
typedef __attribute__((address_space(1))) const uint32_t glb_u32;

static __device__ __forceinline__ ushort f2bf(float f) {
    uint u = __float_as_uint(f);
    uint r = (u + 0x7fffu + ((u >> 16) & 1u)) >> 16;   // RTNE
    return (ushort)r;
}
static __device__ __forceinline__ float bflo(uint v) { return __uint_as_float(v << 16); }
static __device__ __forceinline__ float bfhi(uint v) { return __uint_as_float(v & 0xffff0000u); }

static __device__ __forceinline__ void stage16(const void* g, void* lds) {
    __builtin_amdgcn_global_load_lds((glb_u32*)g, (lds_u32*)lds, 16, 0, 0);
}

// ---------------- histogram over (dst*8+rel) ----------------
__global__ void hist_kernel(const int* __restrict__ dst, const int* __restrict__ et,
                            int* __restrict__ cnt) {
    int e = blockIdx.x * blockDim.x + threadIdx.x;
    if (e < EE) atomicAdd(&cnt[dst[e] * 8 + et[e]], 1);
}

// ---------------- 3-kernel exclusive scan over NB counts ----------------
__global__ __launch_bounds__(1024) void scan1_kernel(const int* __restrict__ cnt,
                                                     int* __restrict__ part,
                                                     int* __restrict__ bsum) {
    __shared__ int sm[1024];
    const int t = threadIdx.x;
    const int g = blockIdx.x * 1024 + t;
    const int v = (g < NB) ? cnt[g] : 0;
    sm[t] = v;
    __syncthreads();
    for (int d = 1; d < 1024; d <<= 1) {
        int u = (t >= d) ? sm[t - d] : 0;
        __syncthreads();
        sm[t] += u;
        __syncthreads();
    }
    if (g < NB) part[g] = sm[t] - v;             // exclusive within block
    if (t == 1023) bsum[blockIdx.x] = sm[1023];  // block total
}

__global__ __launch_bounds__(512) void scan2_kernel(int* __restrict__ bsum, int nblk) {
    __shared__ int sm[512];
    const int t = threadIdx.x;
    const int v = (t < nblk) ? bsum[t] : 0;
    sm[t] = v;
    __syncthreads();
    for (int d = 1; d < 512; d <<= 1) {
        int u = (t >= d) ? sm[t - d] : 0;
        __syncthreads();
        sm[t] += u;
        __syncthreads();
    }
    if (t < nblk) bsum[t] = sm[t] - v;           // exclusive block offsets
}

__global__ __launch_bounds__(1024) void scan3_kernel(const int* __restrict__ part,
                                                     const int* __restrict__ bsum,
                                                     int* __restrict__ off,
                                                     int* __restrict__ cursor) {
    const int g = blockIdx.x * 1024 + threadIdx.x;
    if (g < NB) {
        const int v = part[g] + bsum[blockIdx.x];
        off[g] = v;
        cursor[g] = v;
    }
    if (g == NB) off[NB] = EE;
}

// ---------------- scatter: srcs sorted by (dst,rel) ----------------
__global__ void scatter_kernel(const int* __restrict__ src, const int* __restrict__ dst,
                               const int* __restrict__ et, int* __restrict__ cursor,
                               int* __restrict__ srcs) {
    int e = blockIdx.x * blockDim.x + threadIdx.x;
    if (e < EE) {
        const int b = dst[e] * 8 + et[e];
        const int pos = atomicAdd(&cursor[b], 1);
        srcs[pos] = src[e];
    }
}

// ---------------- x fp32 -> bf16 ----------------
__global__ __launch_bounds__(256) void cvt_x_kernel(const float* __restrict__ x,
                                                    ushort* __restrict__ xb) {
    const int tid = blockIdx.x * blockDim.x + threadIdx.x;   // 800000 threads, 8 elems each
    const size_t i = (size_t)tid * 8;
    const float4 v0 = *reinterpret_cast<const float4*>(x + i);
    const float4 v1 = *reinterpret_cast<const float4*>(x + i + 4);
    uint4 o;
    o.x = (uint)f2bf(v0.x) | ((uint)f2bf(v0.y) << 16);
    o.y = (uint)f2bf(v0.z) | ((uint)f2bf(v0.w) << 16);
    o.z = (uint)f2bf(v1.x) | ((uint)f2bf(v1.y) << 16);
    o.w = (uint)f2bf(v1.z) | ((uint)f2bf(v1.w) << 16);
    *reinterpret_cast<uint4*>(xb + i) = o;
}

// ---------------- weights -> Bt[n][k] bf16, k = [root(128) | W(1024)] ----------------
__global__ __launch_bounds__(256) void prep_w_kernel(const float* __restrict__ root1,
                                                     const float* __restrict__ W1,
                                                     const float* __restrict__ root2,
                                                     const float* __restrict__ W2,
                                                     ushort* __restrict__ Bt1,
                                                     ushort* __restrict__ Bt2) {
    const float* root = blockIdx.y ? root2 : root1;
    const float* W    = blockIdx.y ? W2 : W1;
    ushort* Bt        = blockIdx.y ? Bt2 : Bt1;
    const int n = blockIdx.x;                       // 0..127 output col
    for (int k = threadIdx.x; k < 1152; k += 256) {
        float v = (k < 128) ? root[(size_t)k * 128 + n]
                            : W[(size_t)(k - 128) * 128 + n];
        Bt[(size_t)n * 1152 + k] = f2bf(v);
    }
}

// ---------------- aggregation: one wave per node, 8 segments in parallel ----------------
// lane = g*8 + j : group g handles relation g; lane j holds bytes 32j..32j+31
// of the 256B feature row -> 16 fp32 accumulators, no cross-lane reduction.
__global__ __launch_bounds__(256) void agg_kernel(const int* __restrict__ off,
                                                  const int* __restrict__ srcs,
                                                  const ushort* __restrict__ feat,
                                                  ushort* __restrict__ agg) {
    const int wid = (blockIdx.x * blockDim.x + threadIdx.x) >> 6;
    if (wid >= NN) return;
    const int lane = threadIdx.x & 63;
    const int g = lane >> 3;            // relation group 0..7
    const int j = lane & 7;             // 16-ushort chunk within row

    const int s1 = off[wid * 8 + g + 1];
    int i = off[wid * 8 + g];
    const int cnt = s1 - i;

    float a[16];
#pragma unroll
    for (int k = 0; k < 16; ++k) a[k] = 0.f;

    int p = (i < s1) ? srcs[i] : 0;
    while (__any(i < s1)) {
        const bool act = i < s1;
        const int pn = (i + 1 < s1) ? srcs[i + 1] : 0;    // prefetch next src
        if (act) {
            const ushort* row = feat + (size_t)p * 128 + (j << 4);
            const uint4 v0 = reinterpret_cast<const uint4*>(row)[0];
            const uint4 v1 = reinterpret_cast<const uint4*>(row)[1];
            a[0] += bflo(v0.x);  a[1] += bfhi(v0.x);
            a[2] += bflo(v0.y);  a[3] += bfhi(v0.y);
            a[4] += bflo(v0.z);  a[5] += bfhi(v0.z);
            a[6] += bflo(v0.w);  a[7] += bfhi(v0.w);
            a[8] += bflo(v1.x);  a[9] += bfhi(v1.x);
            a[10] += bflo(v1.y); a[11] += bfhi(v1.y);
            a[12] += bflo(v1.z); a[13] += bfhi(v1.z);
            a[14] += bflo(v1.w); a[15] += bfhi(v1.w);
        }
        p = pn;
        ++i;
    }

    const float inv = 1.0f / (float)max(cnt, 1);
    uint4 o0, o1;
    o0.x = (uint)f2bf(a[0] * inv)  | ((uint)f2bf(a[1] * inv)  << 16);
    o0.y = (uint)f2bf(a[2] * inv)  | ((uint)f2bf(a[3] * inv)  << 16);
    o0.z = (uint)f2bf(a[4] * inv)  | ((uint)f2bf(a[5] * inv)  << 16);
    o0.w = (uint)f2bf(a[6] * inv)  | ((uint)f2bf(a[7] * inv)  << 16);
    o1.x = (uint)f2bf(a[8] * inv)  | ((uint)f2bf(a[9] * inv)  << 16);
    o1.y = (uint)f2bf(a[10] * inv) | ((uint)f2bf(a[11] * inv) << 16);
    o1.z = (uint)f2bf(a[12] * inv) | ((uint)f2bf(a[13] * inv) << 16);
    o1.w = (uint)f2bf(a[14] * inv) | ((uint)f2bf(a[15] * inv) << 16);
    ushort* o = agg + (size_t)wid * 1024 + g * 128 + (j << 4);
    reinterpret_cast<uint4*>(o)[0] = o0;
    reinterpret_cast<uint4*>(o)[1] = o1;
}

// ---------------- MFMA GEMM: h = relu(bias + [xb|agg] @ Bt^T) ----------------
// A logical [N, 1152] bf16 (xb cols 0..127, agg cols 128..1151), Bt [128][1152] bf16.
// Block: 256 thr = 4 waves (2x2), tile 64(M) x 128(N), BK=64, mfma 32x32x16.
// Double-buffered LDS: buf = [A 64x128B (8KB) | B 128x128B (16KB)] x 2 = 48KB.
// LDS is written LINEARLY by global_load_lds; the XOR swizzle ((row&7)<<4) is
// applied on the per-lane GLOBAL source chunk and again on the ds_read side.
__global__ __launch_bounds__(256) void gemm_mfma(const ushort* __restrict__ xb,
                                                 const ushort* __restrict__ agg,
                                                 const ushort* __restrict__ Bt,
                                                 const float* __restrict__ bias,
                                                 ushort* __restrict__ hout) {
    __shared__ __align__(16) uint8_t smem[49152];
    const int t = threadIdx.x;
    const int lane = t & 63;
    const int w = t >> 6;                 // wave 0..3
    const int wr = w >> 1, wc = w & 1;    // 2(M) x 2(N) wave grid
    const int n0 = blockIdx.x * 64;
    const int l31 = lane & 31;
    const int lhalf = lane >> 5;

    f32x16 acc0, acc1;
#pragma unroll
    for (int r = 0; r < 16; ++r) { acc0[r] = 0.f; acc1[r] = 0.f; }

    // fragment read offsets (byte), swizzle = (row&7)<<4
    const int rA = wr * 32 + l31;
    const int aoff = rA * 128, aswz = (rA & 7) << 4;
    const int nB0 = wc * 64 + l31;
    const int nB1 = nB0 + 32;
    const int boff0 = 8192 + nB0 * 128, bswz0 = (nB0 & 7) << 4;
    const int boff1 = 8192 + nB1 * 128, bswz1 = (nB1 & 7) << 4;
    const int ckb = lhalf << 4;           // lane's 16B slot within a 32B k-step

    // staging: per tile, wave w issues 2 A-loads (rows 16w..16w+15) and
    // 4 B-loads (rows 32w..32w+31); each gload_lds = 64 lanes x 16B = 8 rows.
    const int rsub = lane >> 3;                                   // 0..7 row within inst
    const int srcChunk = (((lane & 7) ^ (lane >> 3)) << 4);       // pre-swizzled source chunk
    int garowA[2];
#pragma unroll
    for (int jj = 0; jj < 2; ++jj)
        garowA[jj] = min(n0 + 16 * w + 8 * jj + rsub, NN - 1);    // clamp OOB rows
    size_t bOffG[4];
#pragma unroll
    for (int jj = 0; jj < 4; ++jj)
        bOffG[jj] = (size_t)(32 * w + 8 * jj + rsub) * 2304 + srcChunk;

    const uint8_t* xb8  = (const uint8_t*)xb;
    const uint8_t* agg8 = (const uint8_t*)agg;
    const uint8_t* Bt8  = (const uint8_t*)Bt;

    auto STAGE = [&](int buf, int kt) {
        uint8_t* base = smem + buf * 24576;
        const uint8_t* Asrc; int shift, koffB;
        if (kt < 2) { Asrc = xb8;  shift = 8;  koffB = kt * 128; }          // row=256B
        else        { Asrc = agg8; shift = 11; koffB = (kt - 2) * 128; }    // row=2048B
#pragma unroll
        for (int jj = 0; jj < 2; ++jj)
            stage16(Asrc + (((size_t)garowA[jj]) << shift) + koffB + srcChunk,
                    base + (2 * w + jj) * 1024);
#pragma unroll
        for (int jj = 0; jj < 4; ++jj)
            stage16(Bt8 + bOffG[jj] + kt * 128,
                    base + 8192 + (4 * w + jj) * 1024);
    };

    auto COMPUTE = [&](int buf) {
        const uint8_t* base = smem + buf * 24576;
#pragma unroll
        for (int kb = 0; kb < 4; ++kb) {
            const int cb = kb * 32 + ckb;
            const bf16x8 af = *reinterpret_cast<const bf16x8*>(base + aoff  + (cb ^ aswz));
            const bf16x8 b0 = *reinterpret_cast<const bf16x8*>(base + boff0 + (cb ^ bswz0));
            const bf16x8 b1 = *reinterpret_cast<const bf16x8*>(base + boff1 + (cb ^ bswz1));
            acc0 = __builtin_amdgcn_mfma_f32_32x32x16_bf16(af, b0, acc0, 0, 0, 0);
            acc1 = __builtin_amdgcn_mfma_f32_32x32x16_bf16(af, b1, acc1, 0, 0, 0);
        }
    };

    STAGE(0, 0);
    __syncthreads();                       // implicit vmcnt(0) drain: buf0 ready
    int cur = 0;
#pragma unroll 1
    for (int kt = 0; kt < 17; ++kt) {
        STAGE(cur ^ 1, kt + 1);            // async loads fly under COMPUTE
        COMPUTE(cur);
        __syncthreads();                   // drains vmcnt+lgkmcnt: next buf ready, reads done
        cur ^= 1;
    }
    COMPUTE(cur);

    // epilogue: 32x32 C/D layout: col = lane&31, row = (reg&3)+8*(reg>>2)+4*(lane>>5)
#pragma unroll
    for (int ni = 0; ni < 2; ++ni) {
        const int col = wc * 64 + ni * 32 + l31;
        const float bv = bias[col];
        const f32x16& a = ni ? acc1 : acc0;
#pragma unroll
        for (int reg = 0; reg < 16; ++reg) {
            const int row = n0 + wr * 32 + 4 * lhalf + (reg & 3) + 8 * (reg >> 2);
            if (row < NN) {
                const float v = fmaxf(a[reg] + bv, 0.f);
                hout[(size_t)row * 128 + col] = f2bf(v);
            }
        }
    }
}

// ---------------- head: out[n] = h2[n] . Wout + bout ----------------
__global__ __launch_bounds__(256) void out_kernel(const ushort* __restrict__ h2,
                                                  const float* __restrict__ Wout,
                                                  const float* __restrict__ bout,
                                                  float* __restrict__ outp) {
    const int wid = (blockIdx.x * blockDim.x + threadIdx.x) >> 6;
    if (wid >= NN) return;
    const int lane = threadIdx.x & 63;
    const uint v = *reinterpret_cast<const uint*>(h2 + (size_t)wid * 128 + (lane << 1));
    const float2 ww = *reinterpret_cast<const float2*>(Wout + (lane << 1));
    float s = fmaf(bflo(v), ww.x, bfhi(v) * ww.y);
#pragma unroll
    for (int d = 32; d > 0; d >>= 1) s += __shfl_down(s, d, 64);
    if (lane == 0) outp[wid] = s + bout[0];
}

extern "C" void kernel_launch(void* const* d_in, const int* in_sizes, int n_in,
                              void* d_out, int out_size, void* d_ws, size_t ws_size,
                              hipStream_t stream) {
    const float* x     = (const float*)d_in[0];
    const int*   eidx  = (const int*)  d_in[1];
    const int*   etype = (const int*)  d_in[2];
    const float* W1    = (const float*)d_in[3];
    const float* root1 = (const float*)d_in[4];
    const float* b1    = (const float*)d_in[5];
    const float* W2    = (const float*)d_in[6];
    const float* root2 = (const float*)d_in[7];
    const float* b2    = (const float*)d_in[8];
    const float* Wout  = (const float*)d_in[9];
    const float* bout  = (const float*)d_in[10];
    float* out = (float*)d_out;

    const int* src = eidx;
    const int* dst = eidx + EE;

    char* ws = (char*)d_ws;
    size_t pos = 0;
    auto take = [&](size_t bytes) {
        char* p = ws + pos;
        pos = (pos + bytes + 255) & ~(size_t)255;
        return p;
    };
    int*    cnt    = (int*)   take((size_t)NB * 4);
    int*    off    = (int*)   take((size_t)(NB + 1) * 4);
    int*    cursor = (int*)   take((size_t)NB * 4);
    int*    part   = (int*)   take((size_t)NB * 4);
    int*    bsum   = (int*)   take((size_t)512 * 4);
    int*    srcs   = (int*)   take((size_t)EE * 4);
    ushort* xb     = (ushort*)take((size_t)NN * 128 * 2);
    ushort* h1     = (ushort*)take((size_t)NN * 128 * 2);
    ushort* h2     = (ushort*)take((size_t)NN * 128 * 2);
    ushort* agg    = (ushort*)take((size_t)NN * 1024 * 2);
    ushort* Bt1    = (ushort*)take((size_t)128 * 1152 * 2);
    ushort* Bt2    = (ushort*)take((size_t)128 * 1152 * 2);
    (void)ws_size; (void)n_in; (void)in_sizes; (void)out_size;

    const int eblocks = (EE + 255) / 256;           // 3125
    const int sblocks = (NB + 1023) / 1024;         // 391 scan blocks
    const int wblocks = (NN + 3) / 4;               // 12500 wave-per-node
    const int gblocks = (NN + 63) / 64;             // 782 GEMM tiles

    hipMemsetAsync(cnt, 0, (size_t)NB * 4, stream);
    hist_kernel   <<<eblocks, 256, 0, stream>>>(dst, etype, cnt);
    scan1_kernel  <<<sblocks, 1024, 0, stream>>>(cnt, part, bsum);
    scan2_kernel  <<<1, 512, 0, stream>>>(bsum, sblocks);
    scan3_kernel  <<<sblocks, 1024, 0, stream>>>(part, bsum, off, cursor);
    scatter_kernel<<<eblocks, 256, 0, stream>>>(src, dst, etype, cursor, srcs);
    prep_w_kernel <<<dim3(128, 2), 256, 0, stream>>>(root1, W1, root2, W2, Bt1, Bt2);
    cvt_x_kernel  <<<3125, 256, 0, stream>>>(x, xb);

    // layer 1
    agg_kernel<<<wblocks, 256, 0, stream>>>(off, srcs, xb, agg);
    gemm_mfma <<<gblocks, 256, 0, stream>>>(xb, agg, Bt1, b1, h1);
    // layer 2
    agg_kernel<<<wblocks, 256, 0, stream>>>(off, srcs, h1, agg);
    gemm_mfma <<<gblocks, 256, 0, stream>>>(h1, agg, Bt2, b2, h2);
    // head
    out_kernel<<<wblocks, 256, 0, stream>>>(h2, Wout, bout, out);
}

// Round 6
// 217.063 us; speedup vs baseline: 4.3916x; 1.2757x over previous
//
#include <hip/hip_runtime.h>
#include <hip/hip_bf16.h>

// RGCN regression: N=50000, E=800000, R=8, C=H=128.
// Round 6: sort-prep rewrite (R5 bottleneck: scatter 51us at 0.45% VALU / 15% HBM —
// 800k device-scope atomics + 16x write amplification from cross-XCD line thrash).
//  - 2-level MSD partition: coarse (dst>>8, 196 buckets) with block-aggregated
//    atomics (19k total), then per-bucket LDS sort over 2048 (dlow,et) sub-buckets
//    that emits off[] AND srcs[] densely (no global scans, no per-edge atomics).
// agg (R5), GEMM (R4), head unchanged.

constexpr int NN = 50000;
constexpr int EE = 800000;
constexpr int NB = NN * 8;            // 400000 (dst,rel) buckets
constexpr int NCB = (NN + 255) >> 8;  // 196 coarse buckets
constexpr int EPB = 8192;             // edges per partition block
constexpr int PBLK = (EE + EPB - 1) / EPB;   // 98
constexpr int NSB = 2048;             // sub-buckets per coarse bucket (256 dst x 8 rel)

typedef __attribute__((ext_vector_type(8))) short bf16x8;
typedef __attribute__((ext_vector_type(16))) float f32x16;
typedef __attribute__((address_space(3))) uint32_t lds_u32;
typedef __attribute__((address_space(1))) const uint32_t glb_u32;

static __device__ __forceinline__ ushort f2bf(float f) {
    uint u = __float_as_uint(f);
    uint r = (u + 0x7fffu + ((u >> 16) & 1u)) >> 16;   // RTNE
    return (ushort)r;
}
static __device__ __forceinline__ float bflo(uint v) { return __uint_as_float(v << 16); }
static __device__ __forceinline__ float bfhi(uint v) { return __uint_as_float(v & 0xffff0000u); }

static __device__ __forceinline__ void stage16(const void* g, void* lds) {
    __builtin_amdgcn_global_load_lds((glb_u32*)g, (lds_u32*)lds, 16, 0, 0);
}

// ---------------- P1: coarse histogram (dst>>8), LDS-aggregated ----------------
__global__ __launch_bounds__(1024) void chist_kernel(const int* __restrict__ dst,
                                                     int* __restrict__ ghist) {
    __shared__ int h[NCB];
    const int t = threadIdx.x;
    for (int i = t; i < NCB; i += 1024) h[i] = 0;
    __syncthreads();
    const int e0 = blockIdx.x * EPB + t;
#pragma unroll
    for (int jj = 0; jj < 8; ++jj) {
        const int e = e0 + jj * 1024;
        if (e < EE) atomicAdd(&h[dst[e] >> 8], 1);
    }
    __syncthreads();
    for (int i = t; i < NCB; i += 1024)
        if (h[i]) atomicAdd(&ghist[i], h[i]);
}

// ---------------- P2: scan 196 coarse totals ----------------
__global__ __launch_bounds__(256) void cscan_kernel(const int* __restrict__ ghist,
                                                    int* __restrict__ gstart,
                                                    int* __restrict__ gcur) {
    __shared__ int sm[256];
    const int t = threadIdx.x;
    const int v = (t < NCB) ? ghist[t] : 0;
    sm[t] = v;
    __syncthreads();
    for (int d = 1; d < 256; d <<= 1) {
        int u = (t >= d) ? sm[t - d] : 0;
        __syncthreads();
        sm[t] += u;
        __syncthreads();
    }
    const int excl = sm[t] - v;
    if (t < NCB) { gstart[t] = excl; gcur[t] = excl; }
    if (t == NCB - 1) gstart[NCB] = excl + v;   // == EE
}

// ---------------- P3: coarse partition, block-reserved ranges ----------------
// packed = (dlow<<19) | (et<<16) | src   (src<65536, et<8, dlow<256)
__global__ __launch_bounds__(1024) void cpart_kernel(const int* __restrict__ src,
                                                     const int* __restrict__ dst,
                                                     const int* __restrict__ et,
                                                     int* __restrict__ gcur,
                                                     uint* __restrict__ packed) {
    __shared__ int h[NCB];
    const int t = threadIdx.x;
    for (int i = t; i < NCB; i += 1024) h[i] = 0;
    __syncthreads();
    const int e0 = blockIdx.x * EPB + t;
    int myb[8]; uint mydat[8];
#pragma unroll
    for (int jj = 0; jj < 8; ++jj) {
        const int e = e0 + jj * 1024;
        if (e < EE) {
            const int d = dst[e];
            myb[jj] = d >> 8;
            mydat[jj] = (uint)src[e] | ((uint)et[e] << 16) | ((uint)(d & 255) << 19);
            atomicAdd(&h[myb[jj]], 1);
        } else myb[jj] = -1;
    }
    __syncthreads();
    for (int i = t; i < NCB; i += 1024)
        h[i] = h[i] ? atomicAdd(&gcur[i], h[i]) : 0;   // h becomes running cursor
    __syncthreads();
#pragma unroll
    for (int jj = 0; jj < 8; ++jj) {
        if (myb[jj] >= 0) {
            const int pos = atomicAdd(&h[myb[jj]], 1);
            packed[pos] = mydat[jj];
        }
    }
}

// ---------------- P4: per-coarse-bucket fine sort -> off[] + srcs[] ----------------
__global__ __launch_bounds__(1024) void fsort_kernel(const int* __restrict__ gstart,
                                                     const uint* __restrict__ packed,
                                                     int* __restrict__ off,
                                                     int* __restrict__ srcs) {
    __shared__ int hist[NSB];
    __shared__ int scn[NSB];
    __shared__ int h2[1024];
    const int b = blockIdx.x;
    const int t = threadIdx.x;
    const int s = gstart[b], e = gstart[b + 1];

    for (int i = t; i < NSB; i += 1024) hist[i] = 0;
    __syncthreads();
    for (int i = s + t; i < e; i += 1024)
        atomicAdd(&hist[(packed[i] >> 16) & 0x7FF], 1);
    __syncthreads();
    // exclusive scan over 2048 via pairwise + 1024 Hillis-Steele
    const int a0 = hist[2 * t], a1 = hist[2 * t + 1];
    h2[t] = a0 + a1;
    __syncthreads();
    for (int d = 1; d < 1024; d <<= 1) {
        int u = (t >= d) ? h2[t - d] : 0;
        __syncthreads();
        h2[t] += u;
        __syncthreads();
    }
    const int base = h2[t] - (a0 + a1);
    scn[2 * t] = base;
    scn[2 * t + 1] = base + a0;
    __syncthreads();
    // emit global bucket offsets: gsub = ((b<<8)+dlow)*8+et = (b<<11) + sub
    const int gsubbase = b << 11;
    for (int i = t; i < NSB; i += 1024) {
        const int g = gsubbase + i;
        if (g < NB) off[g] = s + scn[i];
    }
    if (b == NCB - 1 && t == 0) off[NB] = EE;
    __syncthreads();          // off-writes read scn before it becomes a cursor
    for (int i = s + t; i < e; i += 1024) {
        const uint k = packed[i];
        const int pos = atomicAdd(&scn[(k >> 16) & 0x7FF], 1);
        srcs[s + pos] = (int)(k & 0xFFFF);
    }
}

// ---------------- x fp32 -> bf16 ----------------
__global__ __launch_bounds__(256) void cvt_x_kernel(const float* __restrict__ x,
                                                    ushort* __restrict__ xb) {
    const int tid = blockIdx.x * blockDim.x + threadIdx.x;   // 800000 threads, 8 elems each
    const size_t i = (size_t)tid * 8;
    const float4 v0 = *reinterpret_cast<const float4*>(x + i);
    const float4 v1 = *reinterpret_cast<const float4*>(x + i + 4);
    uint4 o;
    o.x = (uint)f2bf(v0.x) | ((uint)f2bf(v0.y) << 16);
    o.y = (uint)f2bf(v0.z) | ((uint)f2bf(v0.w) << 16);
    o.z = (uint)f2bf(v1.x) | ((uint)f2bf(v1.y) << 16);
    o.w = (uint)f2bf(v1.z) | ((uint)f2bf(v1.w) << 16);
    *reinterpret_cast<uint4*>(xb + i) = o;
}

// ---------------- weights -> Bt[n][k] bf16, k = [root(128) | W(1024)] ----------------
__global__ __launch_bounds__(256) void prep_w_kernel(const float* __restrict__ root1,
                                                     const float* __restrict__ W1,
                                                     const float* __restrict__ root2,
                                                     const float* __restrict__ W2,
                                                     ushort* __restrict__ Bt1,
                                                     ushort* __restrict__ Bt2) {
    const float* root = blockIdx.y ? root2 : root1;
    const float* W    = blockIdx.y ? W2 : W1;
    ushort* Bt        = blockIdx.y ? Bt2 : Bt1;
    const int n = blockIdx.x;                       // 0..127 output col
    for (int k = threadIdx.x; k < 1152; k += 256) {
        float v = (k < 128) ? root[(size_t)k * 128 + n]
                            : W[(size_t)(k - 128) * 128 + n];
        Bt[(size_t)n * 1152 + k] = f2bf(v);
    }
}

// ---------------- aggregation: one wave per node, 8 segments in parallel ----------------
// lane = g*8 + j : group g handles relation g; lane j holds bytes 32j..32j+31
// of the 256B feature row -> 16 fp32 accumulators, no cross-lane reduction.
__global__ __launch_bounds__(256) void agg_kernel(const int* __restrict__ off,
                                                  const int* __restrict__ srcs,
                                                  const ushort* __restrict__ feat,
                                                  ushort* __restrict__ agg) {
    const int wid = (blockIdx.x * blockDim.x + threadIdx.x) >> 6;
    if (wid >= NN) return;
    const int lane = threadIdx.x & 63;
    const int g = lane >> 3;            // relation group 0..7
    const int j = lane & 7;             // 16-ushort chunk within row

    const int s1 = off[wid * 8 + g + 1];
    int i = off[wid * 8 + g];
    const int cnt = s1 - i;

    float a[16];
#pragma unroll
    for (int k = 0; k < 16; ++k) a[k] = 0.f;

    int p = (i < s1) ? srcs[i] : 0;
    while (__any(i < s1)) {
        const bool act = i < s1;
        const int pn = (i + 1 < s1) ? srcs[i + 1] : 0;    // prefetch next src
        if (act) {
            const ushort* row = feat + (size_t)p * 128 + (j << 4);
            const uint4 v0 = reinterpret_cast<const uint4*>(row)[0];
            const uint4 v1 = reinterpret_cast<const uint4*>(row)[1];
            a[0] += bflo(v0.x);  a[1] += bfhi(v0.x);
            a[2] += bflo(v0.y);  a[3] += bfhi(v0.y);
            a[4] += bflo(v0.z);  a[5] += bfhi(v0.z);
            a[6] += bflo(v0.w);  a[7] += bfhi(v0.w);
            a[8] += bflo(v1.x);  a[9] += bfhi(v1.x);
            a[10] += bflo(v1.y); a[11] += bfhi(v1.y);
            a[12] += bflo(v1.z); a[13] += bfhi(v1.z);
            a[14] += bflo(v1.w); a[15] += bfhi(v1.w);
        }
        p = pn;
        ++i;
    }

    const float inv = 1.0f / (float)max(cnt, 1);
    uint4 o0, o1;
    o0.x = (uint)f2bf(a[0] * inv)  | ((uint)f2bf(a[1] * inv)  << 16);
    o0.y = (uint)f2bf(a[2] * inv)  | ((uint)f2bf(a[3] * inv)  << 16);
    o0.z = (uint)f2bf(a[4] * inv)  | ((uint)f2bf(a[5] * inv)  << 16);
    o0.w = (uint)f2bf(a[6] * inv)  | ((uint)f2bf(a[7] * inv)  << 16);
    o1.x = (uint)f2bf(a[8] * inv)  | ((uint)f2bf(a[9] * inv)  << 16);
    o1.y = (uint)f2bf(a[10] * inv) | ((uint)f2bf(a[11] * inv) << 16);
    o1.z = (uint)f2bf(a[12] * inv) | ((uint)f2bf(a[13] * inv) << 16);
    o1.w = (uint)f2bf(a[14] * inv) | ((uint)f2bf(a[15] * inv) << 16);
    ushort* o = agg + (size_t)wid * 1024 + g * 128 + (j << 4);
    reinterpret_cast<uint4*>(o)[0] = o0;
    reinterpret_cast<uint4*>(o)[1] = o1;
}

// ---------------- MFMA GEMM: h = relu(bias + [xb|agg] @ Bt^T) ----------------
// A logical [N, 1152] bf16 (xb cols 0..127, agg cols 128..1151), Bt [128][1152] bf16.
// Block: 256 thr = 4 waves (2x2), tile 64(M) x 128(N), BK=64, mfma 32x32x16.
// Double-buffered LDS: buf = [A 64x128B (8KB) | B 128x128B (16KB)] x 2 = 48KB.
// LDS is written LINEARLY by global_load_lds; the XOR swizzle ((row&7)<<4) is
// applied on the per-lane GLOBAL source chunk and again on the ds_read side.
__global__ __launch_bounds__(256) void gemm_mfma(const ushort* __restrict__ xb,
                                                 const ushort* __restrict__ agg,
                                                 const ushort* __restrict__ Bt,
                                                 const float* __restrict__ bias,
                                                 ushort* __restrict__ hout) {
    __shared__ __align__(16) uint8_t smem[49152];
    const int t = threadIdx.x;
    const int lane = t & 63;
    const int w = t >> 6;                 // wave 0..3
    const int wr = w >> 1, wc = w & 1;    // 2(M) x 2(N) wave grid
    const int n0 = blockIdx.x * 64;
    const int l31 = lane & 31;
    const int lhalf = lane >> 5;

    f32x16 acc0, acc1;
#pragma unroll
    for (int r = 0; r < 16; ++r) { acc0[r] = 0.f; acc1[r] = 0.f; }

    // fragment read offsets (byte), swizzle = (row&7)<<4
    const int rA = wr * 32 + l31;
    const int aoff = rA * 128, aswz = (rA & 7) << 4;
    const int nB0 = wc * 64 + l31;
    const int nB1 = nB0 + 32;
    const int boff0 = 8192 + nB0 * 128, bswz0 = (nB0 & 7) << 4;
    const int boff1 = 8192 + nB1 * 128, bswz1 = (nB1 & 7) << 4;
    const int ckb = lhalf << 4;           // lane's 16B slot within a 32B k-step

    // staging: per tile, wave w issues 2 A-loads (rows 16w..16w+15) and
    // 4 B-loads (rows 32w..32w+31); each gload_lds = 64 lanes x 16B = 8 rows.
    const int rsub = lane >> 3;                                   // 0..7 row within inst
    const int srcChunk = (((lane & 7) ^ (lane >> 3)) << 4);       // pre-swizzled source chunk
    int garowA[2];
#pragma unroll
    for (int jj = 0; jj < 2; ++jj)
        garowA[jj] = min(n0 + 16 * w + 8 * jj + rsub, NN - 1);    // clamp OOB rows
    size_t bOffG[4];
#pragma unroll
    for (int jj = 0; jj < 4; ++jj)
        bOffG[jj] = (size_t)(32 * w + 8 * jj + rsub) * 2304 + srcChunk;

    const uint8_t* xb8  = (const uint8_t*)xb;
    const uint8_t* agg8 = (const uint8_t*)agg;
    const uint8_t* Bt8  = (const uint8_t*)Bt;

    auto STAGE = [&](int buf, int kt) {
        uint8_t* base = smem + buf * 24576;
        const uint8_t* Asrc; int shift, koffB;
        if (kt < 2) { Asrc = xb8;  shift = 8;  koffB = kt * 128; }          // row=256B
        else        { Asrc = agg8; shift = 11; koffB = (kt - 2) * 128; }    // row=2048B
#pragma unroll
        for (int jj = 0; jj < 2; ++jj)
            stage16(Asrc + (((size_t)garowA[jj]) << shift) + koffB + srcChunk,
                    base + (2 * w + jj) * 1024);
#pragma unroll
        for (int jj = 0; jj < 4; ++jj)
            stage16(Bt8 + bOffG[jj] + kt * 128,
                    base + 8192 + (4 * w + jj) * 1024);
    };

    auto COMPUTE = [&](int buf) {
        const uint8_t* base = smem + buf * 24576;
#pragma unroll
        for (int kb = 0; kb < 4; ++kb) {
            const int cb = kb * 32 + ckb;
            const bf16x8 af = *reinterpret_cast<const bf16x8*>(base + aoff  + (cb ^ aswz));
            const bf16x8 b0 = *reinterpret_cast<const bf16x8*>(base + boff0 + (cb ^ bswz0));
            const bf16x8 b1 = *reinterpret_cast<const bf16x8*>(base + boff1 + (cb ^ bswz1));
            acc0 = __builtin_amdgcn_mfma_f32_32x32x16_bf16(af, b0, acc0, 0, 0, 0);
            acc1 = __builtin_amdgcn_mfma_f32_32x32x16_bf16(af, b1, acc1, 0, 0, 0);
        }
    };

    STAGE(0, 0);
    __syncthreads();                       // implicit vmcnt(0) drain: buf0 ready
    int cur = 0;
#pragma unroll 1
    for (int kt = 0; kt < 17; ++kt) {
        STAGE(cur ^ 1, kt + 1);            // async loads fly under COMPUTE
        COMPUTE(cur);
        __syncthreads();                   // drains vmcnt+lgkmcnt: next buf ready, reads done
        cur ^= 1;
    }
    COMPUTE(cur);

    // epilogue: 32x32 C/D layout: col = lane&31, row = (reg&3)+8*(reg>>2)+4*(lane>>5)
#pragma unroll
    for (int ni = 0; ni < 2; ++ni) {
        const int col = wc * 64 + ni * 32 + l31;
        const float bv = bias[col];
        const f32x16& a = ni ? acc1 : acc0;
#pragma unroll
        for (int reg = 0; reg < 16; ++reg) {
            const int row = n0 + wr * 32 + 4 * lhalf + (reg & 3) + 8 * (reg >> 2);
            if (row < NN) {
                const float v = fmaxf(a[reg] + bv, 0.f);
                hout[(size_t)row * 128 + col] = f2bf(v);
            }
        }
    }
}

// ---------------- head: out[n] = h2[n] . Wout + bout ----------------
__global__ __launch_bounds__(256) void out_kernel(const ushort* __restrict__ h2,
                                                  const float* __restrict__ Wout,
                                                  const float* __restrict__ bout,
                                                  float* __restrict__ outp) {
    const int wid = (blockIdx.x * blockDim.x + threadIdx.x) >> 6;
    if (wid >= NN) return;
    const int lane = threadIdx.x & 63;
    const uint v = *reinterpret_cast<const uint*>(h2 + (size_t)wid * 128 + (lane << 1));
    const float2 ww = *reinterpret_cast<const float2*>(Wout + (lane << 1));
    float s = fmaf(bflo(v), ww.x, bfhi(v) * ww.y);
#pragma unroll
    for (int d = 32; d > 0; d >>= 1) s += __shfl_down(s, d, 64);
    if (lane == 0) outp[wid] = s + bout[0];
}

extern "C" void kernel_launch(void* const* d_in, const int* in_sizes, int n_in,
                              void* d_out, int out_size, void* d_ws, size_t ws_size,
                              hipStream_t stream) {
    const float* x     = (const float*)d_in[0];
    const int*   eidx  = (const int*)  d_in[1];
    const int*   etype = (const int*)  d_in[2];
    const float* W1    = (const float*)d_in[3];
    const float* root1 = (const float*)d_in[4];
    const float* b1    = (const float*)d_in[5];
    const float* W2    = (const float*)d_in[6];
    const float* root2 = (const float*)d_in[7];
    const float* b2    = (const float*)d_in[8];
    const float* Wout  = (const float*)d_in[9];
    const float* bout  = (const float*)d_in[10];
    float* out = (float*)d_out;

    const int* src = eidx;
    const int* dst = eidx + EE;

    char* ws = (char*)d_ws;
    size_t pos = 0;
    auto take = [&](size_t bytes) {
        char* p = ws + pos;
        pos = (pos + bytes + 255) & ~(size_t)255;
        return p;
    };
    int*    ghist  = (int*)   take((size_t)NCB * 4);
    int*    gstart = (int*)   take((size_t)(NCB + 1) * 4);
    int*    gcur   = (int*)   take((size_t)NCB * 4);
    uint*   packed = (uint*)  take((size_t)EE * 4);
    int*    off    = (int*)   take((size_t)(NB + 1) * 4);
    int*    srcs   = (int*)   take((size_t)EE * 4);
    ushort* xb     = (ushort*)take((size_t)NN * 128 * 2);
    ushort* h1     = (ushort*)take((size_t)NN * 128 * 2);
    ushort* h2     = (ushort*)take((size_t)NN * 128 * 2);
    ushort* agg    = (ushort*)take((size_t)NN * 1024 * 2);
    ushort* Bt1    = (ushort*)take((size_t)128 * 1152 * 2);
    ushort* Bt2    = (ushort*)take((size_t)128 * 1152 * 2);
    (void)ws_size; (void)n_in; (void)in_sizes; (void)out_size;

    const int wblocks = (NN + 3) / 4;               // 12500 wave-per-node
    const int gblocks = (NN + 63) / 64;             // 782 GEMM tiles

    hipMemsetAsync(ghist, 0, (size_t)NCB * 4, stream);
    chist_kernel<<<PBLK, 1024, 0, stream>>>(dst, ghist);
    cscan_kernel<<<1, 256, 0, stream>>>(ghist, gstart, gcur);
    cpart_kernel<<<PBLK, 1024, 0, stream>>>(src, dst, etype, gcur, packed);
    fsort_kernel<<<NCB, 1024, 0, stream>>>(gstart, packed, off, srcs);
    prep_w_kernel<<<dim3(128, 2), 256, 0, stream>>>(root1, W1, root2, W2, Bt1, Bt2);
    cvt_x_kernel <<<3125, 256, 0, stream>>>(x, xb);

    // layer 1
    agg_kernel<<<wblocks, 256, 0, stream>>>(off, srcs, xb, agg);
    gemm_mfma <<<gblocks, 256, 0, stream>>>(xb, agg, Bt1, b1, h1);
    // layer 2
    agg_kernel<<<wblocks, 256, 0, stream>>>(off, srcs, h1, agg);
    gemm_mfma <<<gblocks, 256, 0, stream>>>(h1, agg, Bt2, b2, h2);
    // head
    out_kernel<<<wblocks, 256, 0, stream>>>(h2, Wout, bout, out);
}